// Round 13
// baseline (649.288 us; speedup 1.0000x reference)
//
#include <hip/hip_runtime.h>
#include <hip/hip_bf16.h>

#define BB 4096
#define DD 64
#define HH 512

typedef __hip_bfloat16 bf16;
typedef __attribute__((ext_vector_type(8))) short bf16x8;
typedef __attribute__((ext_vector_type(4))) float f32x4;

__device__ __forceinline__ float bf2f(bf16 x) { return __bfloat162float(x); }
__device__ __forceinline__ float u16tof(unsigned short u) {
  union { unsigned int i; float f; } v; v.i = ((unsigned int)u) << 16; return v.f;
}

// ws: Xbf (B*H bf16) | Ybf (B*H bf16) | W2bf | V2bf (H*H bf16) |
//     W1T (64x512 bf16) | Jpart (2 x B x 64 f32)  total ~11.1 MB
// Q_diag stashed f32 in out[:,64:] by k3(act=1); combine() adds 2*J*sig.

// ---------------------------------------------------------------------------
// cvt: [0,256) W2bf; [256,512) V2bf; [512,544) W1T[d*512+k] = W1[k*64+d].
// ---------------------------------------------------------------------------
__global__ __launch_bounds__(256) void cvt_weights(
    const float* __restrict__ W2, const float* __restrict__ V2,
    const float* __restrict__ W1,
    bf16* __restrict__ W2bf, bf16* __restrict__ V2bf, bf16* __restrict__ W1T) {
  int blk = blockIdx.x, t = threadIdx.x;
  if (blk < 512) {
    const float* src = (blk < 256) ? W2 : V2;
    bf16* dst = (blk < 256) ? W2bf : V2bf;
    int i = ((blk & 255) * 256 + t) * 4;
    float4 v = *(const float4*)(src + i);
    bf16 o[4] = {__float2bfloat16(v.x), __float2bfloat16(v.y),
                 __float2bfloat16(v.z), __float2bfloat16(v.w)};
    *(uint2*)(dst + i) = *(uint2*)o;
  } else {
    int e = (blk - 512) * 1024 + t * 4;
    int d = e >> 9, k0 = e & 511;
    bf16 o[4];
#pragma unroll
    for (int j = 0; j < 4; ++j) o[j] = __float2bfloat16(W1[(size_t)(k0 + j) * 64 + d]);
    *(uint2*)(W1T + e) = *(uint2*)o;
  }
}

// ---------------------------------------------------------------------------
// k1: Xbf = bf16(tanh(mu @ W^T + bias)), K=64.
// ---------------------------------------------------------------------------
__global__ __launch_bounds__(256) void k1_stage1(
    const float* __restrict__ states,
    const float* __restrict__ W, const float* __restrict__ bias,
    bf16* __restrict__ out) {
  __shared__ __align__(16) float aT[64 * 68];
  __shared__ __align__(16) float wT[64 * 68];
  const int bt = blockIdx.x * 64;
  const int ht = blockIdx.y * 64;
  const int t = threadIdx.x;

#pragma unroll
  for (int i = 0; i < 16; ++i) {
    int idx = t + i * 256;
    int r = idx >> 6, k = idx & 63;
    aT[k * 68 + r] = states[(size_t)(bt + r) * 128 + k];
    wT[k * 68 + r] = W[(size_t)(ht + r) * 64 + k];
  }
  __syncthreads();

  const int bi = (t & 15) * 4, hj = (t >> 4) * 4;
  float acc[4][4] = {};
#pragma unroll
  for (int k = 0; k < 64; ++k) {
    float4 av = *(const float4*)(aT + k * 68 + bi);
    float4 bv = *(const float4*)(wT + k * 68 + hj);
    float ar[4] = {av.x, av.y, av.z, av.w};
    float br[4] = {bv.x, bv.y, bv.z, bv.w};
#pragma unroll
    for (int i = 0; i < 4; ++i)
#pragma unroll
      for (int j = 0; j < 4; ++j) acc[i][j] += ar[i] * br[j];
  }
#pragma unroll
  for (int j = 0; j < 4; ++j) {
    float bsv = bias[ht + hj + j];
#pragma unroll
    for (int i = 0; i < 4; ++i)
      out[(size_t)(bt + bi + i) * HH + ht + hj + j] =
          __float2bfloat16(tanhf(acc[i][j] + bsv));
  }
}

// ---------------------------------------------------------------------------
// k2 (MFMA): Ybf = bf16(tanh(Xbf @ Wbf^T + bias)). K=512. 64x64 tiles.
// ---------------------------------------------------------------------------
__global__ __launch_bounds__(256) void k2_mfma(
    const bf16* __restrict__ A, const bf16* __restrict__ Wbf,
    const float* __restrict__ bias, bf16* __restrict__ out) {
  __shared__ __align__(16) bf16 As[64 * 72];
  __shared__ __align__(16) bf16 Bs[64 * 72];
  const int bt = blockIdx.x * 64;
  const int ht = blockIdx.y * 64;
  const int t = threadIdx.x;
  const int lane = t & 63;
  const int w = t >> 6, wm = w & 1, wn = w >> 1;
  const int c = lane & 15, q = lane >> 4;

  f32x4 acc[2][2] = {};
  for (int kc = 0; kc < 8; ++kc) {
    __syncthreads();
#pragma unroll
    for (int i = 0; i < 2; ++i) {
      int u = t + i * 256;
      int row = u >> 3, kb = (u & 7) * 8;
      *(uint4*)(As + row * 72 + kb) =
          *(const uint4*)(A + (size_t)(bt + row) * HH + kc * 64 + kb);
      *(uint4*)(Bs + row * 72 + kb) =
          *(const uint4*)(Wbf + (size_t)(ht + row) * HH + kc * 64 + kb);
    }
    __syncthreads();
#pragma unroll
    for (int s = 0; s < 2; ++s) {
      bf16x8 af[2], bfr[2];
#pragma unroll
      for (int mt = 0; mt < 2; ++mt)
        af[mt] = __builtin_bit_cast(bf16x8,
            *(const uint4*)(As + (wm * 32 + mt * 16 + c) * 72 + s * 32 + q * 8));
#pragma unroll
      for (int nt = 0; nt < 2; ++nt)
        bfr[nt] = __builtin_bit_cast(bf16x8,
            *(const uint4*)(Bs + (wn * 32 + nt * 16 + c) * 72 + s * 32 + q * 8));
#pragma unroll
      for (int mt = 0; mt < 2; ++mt)
#pragma unroll
        for (int nt = 0; nt < 2; ++nt)
          acc[mt][nt] = __builtin_amdgcn_mfma_f32_16x16x32_bf16(
              af[mt], bfr[nt], acc[mt][nt], 0, 0, 0);
    }
  }
#pragma unroll
  for (int nt = 0; nt < 2; ++nt) {
    int col = ht + wn * 32 + nt * 16 + c;
    float bs = bias[col];
#pragma unroll
    for (int mt = 0; mt < 2; ++mt)
#pragma unroll
      for (int r = 0; r < 4; ++r) {
        int b = bt + wm * 32 + mt * 16 + q * 4 + r;
        out[(size_t)b * HH + col] = __float2bfloat16(tanhf(acc[mt][nt][r] + bs));
      }
  }
}

// ---------------------------------------------------------------------------
// k3: tmp = A @ W^T + bias (A bf16 Bx512, W f32 64x512). act? softplus. f32 out.
// ---------------------------------------------------------------------------
__global__ __launch_bounds__(256) void k3_stage3(
    const bf16* __restrict__ A,
    const float* __restrict__ W, const float* __restrict__ bias,
    float* __restrict__ out, int colOff, int act) {
  __shared__ __align__(16) float aT[32 * 68];
  __shared__ __align__(16) float wT[32 * 68];
  const int bt = blockIdx.x * 64;
  const int t = threadIdx.x;
  const int bi = (t & 15) * 4, oj = (t >> 4) * 4;
  float acc[4][4] = {};

  for (int kc = 0; kc < HH; kc += 32) {
    {
      int row = t >> 2, kb = (t & 3) * 8;
      uint4 raw = *(const uint4*)(A + (size_t)(bt + row) * HH + kc + kb);
      const unsigned short* xs = (const unsigned short*)&raw;
#pragma unroll
      for (int j = 0; j < 8; ++j) aT[(kb + j) * 68 + row] = u16tof(xs[j]);
    }
#pragma unroll
    for (int i = 0; i < 8; ++i) {
      int idx = t + i * 256;
      int r = idx >> 5, k = idx & 31;
      wT[k * 68 + r] = W[(size_t)r * HH + kc + k];
    }
    __syncthreads();
#pragma unroll
    for (int k = 0; k < 32; ++k) {
      float4 av = *(const float4*)(aT + k * 68 + bi);
      float4 bv = *(const float4*)(wT + k * 68 + oj);
      float ar[4] = {av.x, av.y, av.z, av.w};
      float br[4] = {bv.x, bv.y, bv.z, bv.w};
#pragma unroll
      for (int i = 0; i < 4; ++i)
#pragma unroll
        for (int j = 0; j < 4; ++j) acc[i][j] += ar[i] * br[j];
    }
    __syncthreads();
  }
#pragma unroll
  for (int j = 0; j < 4; ++j) {
    float bsv = bias[oj + j];
#pragma unroll
    for (int i = 0; i < 4; ++i) {
      float v = acc[i][j] + bsv;
      if (act) v = fmaxf(v, 0.0f) + log1pf(expf(-fabsf(v)));
      out[(size_t)(bt + bi + i) * 128 + colOff + oj + j] = v;
    }
  }
}

// ---------------------------------------------------------------------------
// k4 v7: grid (2048 bt, 2 hp), tile 128M x 256N, BK=64. M = 2b x 64d flatten.
// As built once/kc (halved redundancy); Bs = 256-row pure copy; 64 MFMA/wave/kc.
// Epilogue: w3s(64x264 bf16) + d2f staged into reused As/Bs space.
// LDS ~62.5 KB -> 2 blocks/CU. acc 4x8 f32x4 = 128 VGPR.
// ---------------------------------------------------------------------------
__global__ __launch_bounds__(256) void k4_gemm(
    const bf16* __restrict__ Xbf, const bf16* __restrict__ Ybf,
    const bf16* __restrict__ W1T, const bf16* __restrict__ W2bf,
    const float* __restrict__ W3, float* __restrict__ Jpart) {
  __shared__ __align__(16) bf16 ABs[128 * 72 + 256 * 72];  // As|Bs; epilogue w3s
  __shared__ __align__(16) float d1f[2 * 512];
  __shared__ __align__(16) float d2f[2 * 256];
  __shared__ float red[2 * 128];
  bf16* As = ABs;
  bf16* Bs = ABs + 128 * 72;
  const int bt = blockIdx.x;            // b-pair
  const int h0 = blockIdx.y * 256;
  const int t = threadIdx.x;
  const int lane = t & 63;
  const int w = t >> 6, wm = w & 1, wn = w >> 1;
  const int c = lane & 15, q = lane >> 4;

  // d1f = 1 - h1^2 (2 rows x 512 f32)
#pragma unroll
  for (int i = 0; i < 4; ++i) {
    int e = t + i * 256;
    float x = bf2f(Xbf[(size_t)(bt * 2 + (e >> 9)) * HH + (e & 511)]);
    d1f[e] = 1.0f - x * x;
  }
  __syncthreads();

  f32x4 acc[4][8] = {};
  for (int kc = 0; kc < 8; ++kc) {
    // copy Bs (256 x 64) — pure copy, issue global loads early
#pragma unroll
    for (int i = 0; i < 8; ++i) {
      int g = t + i * 256;
      int row = g >> 3, kb = (g & 7) * 8;
      *(uint4*)(Bs + row * 72 + kb) =
          *(const uint4*)(W2bf + (size_t)(h0 + row) * HH + kc * 64 + kb);
    }
    // build As (128 x 64): m = bb*64 + dl, A = d1f * W1T
#pragma unroll
    for (int i = 0; i < 4; ++i) {
      int g = t + i * 256;
      int m = g >> 3, kb = (g & 7) * 8;
      int bb = m >> 6, dl = m & 63;
      uint4 w1r = *(const uint4*)(W1T + (size_t)dl * HH + kc * 64 + kb);
      const unsigned short* ws_ = (const unsigned short*)&w1r;
      const float* dp = d1f + bb * 512 + kc * 64 + kb;
      bf16 oa[8];
#pragma unroll
      for (int j = 0; j < 8; ++j)
        oa[j] = __float2bfloat16(dp[j] * u16tof(ws_[j]));
      *(uint4*)(As + m * 72 + kb) = *(const uint4*)oa;
    }
    __syncthreads();
#pragma unroll
    for (int s = 0; s < 2; ++s) {
      bf16x8 af[4], bfr[8];
#pragma unroll
      for (int mt = 0; mt < 4; ++mt)
        af[mt] = __builtin_bit_cast(bf16x8,
            *(const uint4*)(As + (wm * 64 + mt * 16 + c) * 72 + s * 32 + q * 8));
#pragma unroll
      for (int nt = 0; nt < 8; ++nt)
        bfr[nt] = __builtin_bit_cast(bf16x8,
            *(const uint4*)(Bs + (wn * 128 + nt * 16 + c) * 72 + s * 32 + q * 8));
#pragma unroll
      for (int mt = 0; mt < 4; ++mt)
#pragma unroll
        for (int nt = 0; nt < 8; ++nt)
          acc[mt][nt] = __builtin_amdgcn_mfma_f32_16x16x32_bf16(
              af[mt], bfr[nt], acc[mt][nt], 0, 0, 0);
    }
    __syncthreads();   // all frag reads done before next staging overwrite
  }

  // ---- epilogue: stage d2f + w3s (reusing ABs), fold, reduce, write ----
  bf16* w3s = ABs;  // 64 x 264 bf16 = 33792 B <= 55296 B available
#pragma unroll
  for (int i = 0; i < 2; ++i) {
    int e = t + i * 256;
    float y = bf2f(Ybf[(size_t)(bt * 2 + (e >> 8)) * HH + h0 + (e & 255)]);
    d2f[e] = 1.0f - y * y;
  }
#pragma unroll
  for (int i = 0; i < 16; ++i) {
    int e = (t + i * 256) * 4;          // 64*256 elems in groups of 4
    int dl = e >> 8, hl = e & 255;
    float4 v = *(const float4*)(W3 + (size_t)dl * HH + h0 + hl);
    bf16 o[4] = {__float2bfloat16(v.x), __float2bfloat16(v.y),
                 __float2bfloat16(v.z), __float2bfloat16(v.w)};
    *(uint2*)(w3s + dl * 264 + hl) = *(uint2*)o;
  }
  __syncthreads();

#pragma unroll
  for (int mt = 0; mt < 4; ++mt) {
#pragma unroll
    for (int r = 0; r < 4; ++r) {
      int m = wm * 64 + mt * 16 + q * 4 + r;
      int bb = m >> 6, dl = m & 63;
      float v = 0.f;
#pragma unroll
      for (int nt = 0; nt < 8; ++nt) {
        int n = wn * 128 + nt * 16 + c;
        v += acc[mt][nt][r] * d2f[bb * 256 + n] * bf2f(w3s[dl * 264 + n]);
      }
      v += __shfl_xor(v, 1);
      v += __shfl_xor(v, 2);
      v += __shfl_xor(v, 4);
      v += __shfl_xor(v, 8);
      if (c == 0) red[wn * 128 + m] = v;
    }
  }
  __syncthreads();
  if (t < 128) {
    float J = red[t] + red[128 + t];
    Jpart[(size_t)blockIdx.y * (BB * 64) + (size_t)bt * 128 + t] = J;
  }
}

// ---------------------------------------------------------------------------
// combine: out[b,64+d] = 2*(Jpart plane0 + plane1)*sigma + out (Qd stash)
// ---------------------------------------------------------------------------
__global__ __launch_bounds__(256) void combine(
    const float* __restrict__ Jpart, const float* __restrict__ states,
    float* __restrict__ out) {
  int idx = blockIdx.x * 256 + threadIdx.x;
  int b = idx >> 6, d = idx & 63;
  const int plane = BB * 64;
  float J = Jpart[idx] + Jpart[plane + idx];
  float sig = states[(size_t)b * 128 + 64 + d];
  float qd = out[(size_t)b * 128 + 64 + d];
  out[(size_t)b * 128 + 64 + d] = 2.0f * J * sig + qd;
}

extern "C" void kernel_launch(void* const* d_in, const int* in_sizes, int n_in,
                              void* d_out, int out_size, void* d_ws, size_t ws_size,
                              hipStream_t stream) {
  // inputs: 0:t 1:states 2:W1 3:b1 4:W2 5:b2 6:W3 7:b3 8:V1 9:c1 10:V2 11:c2 12:V3 13:c3
  const float* states = (const float*)d_in[1];
  const float* W1 = (const float*)d_in[2];
  const float* b1 = (const float*)d_in[3];
  const float* W2 = (const float*)d_in[4];
  const float* b2 = (const float*)d_in[5];
  const float* W3 = (const float*)d_in[6];
  const float* b3 = (const float*)d_in[7];
  const float* V1 = (const float*)d_in[8];
  const float* c1 = (const float*)d_in[9];
  const float* V2 = (const float*)d_in[10];
  const float* c2 = (const float*)d_in[11];
  const float* V3 = (const float*)d_in[12];
  const float* c3 = (const float*)d_in[13];
  float* out = (float*)d_out;

  bf16* Xbf = (bf16*)d_ws;                         // B*H  (4 MB)
  bf16* Ybf = Xbf + (size_t)BB * HH;               // B*H  (4 MB)
  bf16* W2bf = Ybf + (size_t)BB * HH;              // H*H  (0.5 MB)
  bf16* V2bf = W2bf + (size_t)HH * HH;             // H*H  (0.5 MB)
  bf16* W1T = V2bf + (size_t)HH * HH;              // 64x512 (64 KB)
  float* Jpart = (float*)(W1T + (size_t)DD * HH);  // 2*B*64 f32 (2 MB)

  cvt_weights<<<dim3(544), 256, 0, stream>>>(W2, V2, W1, W2bf, V2bf, W1T);
  // Q path; stash Q_diag (softplus, f32) into out[:, 64:]
  k1_stage1<<<dim3(64, 8), 256, 0, stream>>>(states, V1, c1, Xbf);       // g1
  k2_mfma<<<dim3(64, 8), 256, 0, stream>>>(Xbf, V2bf, c2, Ybf);          // g2
  k3_stage3<<<dim3(64), 256, 0, stream>>>(Ybf, V3, c3, out, 64, 1);      // Qd
  // h path
  k1_stage1<<<dim3(64, 8), 256, 0, stream>>>(states, W1, b1, Xbf);       // h1
  k2_mfma<<<dim3(64, 8), 256, 0, stream>>>(Xbf, W2bf, b2, Ybf);          // h2
  k3_stage3<<<dim3(64), 256, 0, stream>>>(Ybf, W3, b3, out, 0, 0);       // mu
  // J_diag ((b,d)-flattened GEMM, N=256 per block) + final combine
  k4_gemm<<<dim3(2048, 2), 256, 0, stream>>>(Xbf, Ybf, W1T, W2bf, W3, Jpart);
  combine<<<dim3(1024), 256, 0, stream>>>(Jpart, states, out);
}

// Round 14
// 488.638 us; speedup vs baseline: 1.3288x; 1.3288x over previous
//
#include <hip/hip_runtime.h>
#include <hip/hip_bf16.h>

#define BB 4096
#define DD 64
#define HH 512

typedef __hip_bfloat16 bf16;
typedef __attribute__((ext_vector_type(8))) short bf16x8;
typedef __attribute__((ext_vector_type(4))) float f32x4;

__device__ __forceinline__ float bf2f(bf16 x) { return __bfloat162float(x); }
__device__ __forceinline__ float u16tof(unsigned short u) {
  union { unsigned int i; float f; } v; v.i = ((unsigned int)u) << 16; return v.f;
}
#define BC8(p) __builtin_bit_cast(bf16x8, *(const uint4*)(p))

// ws: Xbf | Ybf (B*H bf16) | W2bf | V2bf (H*H bf16) |
//     W1T | W1bf | V1bf | W3bf | V3bf (64x512-class bf16)   ~9.3 MB
// fwd writes mu -> out[:, :64] and Qd -> out[:, 64:]; k4 RMWs out[:, 64:].

// ---------------------------------------------------------------------------
// cvt: [0,256) W2bf; [256,512) V2bf; [512,544) W1T[d*512+k]=W1[k*64+d];
//      [544,672): natural bf16 cvt of W1, V1, W3, V3 (32 blocks each).
// ---------------------------------------------------------------------------
__global__ __launch_bounds__(256) void cvt_weights(
    const float* __restrict__ W2, const float* __restrict__ V2,
    const float* __restrict__ W1, const float* __restrict__ V1,
    const float* __restrict__ W3, const float* __restrict__ V3,
    bf16* __restrict__ W2bf, bf16* __restrict__ V2bf, bf16* __restrict__ W1T,
    bf16* __restrict__ W1bf, bf16* __restrict__ V1bf,
    bf16* __restrict__ W3bf, bf16* __restrict__ V3bf) {
  int blk = blockIdx.x, t = threadIdx.x;
  if (blk < 512) {
    const float* src = (blk < 256) ? W2 : V2;
    bf16* dst = (blk < 256) ? W2bf : V2bf;
    int i = ((blk & 255) * 256 + t) * 4;
    float4 v = *(const float4*)(src + i);
    bf16 o[4] = {__float2bfloat16(v.x), __float2bfloat16(v.y),
                 __float2bfloat16(v.z), __float2bfloat16(v.w)};
    *(uint2*)(dst + i) = *(uint2*)o;
  } else if (blk < 544) {
    int e = (blk - 512) * 1024 + t * 4;
    int d = e >> 9, k0 = e & 511;
    bf16 o[4];
#pragma unroll
    for (int j = 0; j < 4; ++j) o[j] = __float2bfloat16(W1[(size_t)(k0 + j) * 64 + d]);
    *(uint2*)(W1T + e) = *(uint2*)o;
  } else {
    int which = (blk - 544) >> 5;
    int local = (blk - 544) & 31;
    const float* src = (which == 0) ? W1 : (which == 1) ? V1 : (which == 2) ? W3 : V3;
    bf16* dst = (which == 0) ? W1bf : (which == 1) ? V1bf : (which == 2) ? W3bf : V3bf;
    int i = (local * 256 + t) * 4;
    float4 v = *(const float4*)(src + i);
    bf16 o[4] = {__float2bfloat16(v.x), __float2bfloat16(v.y),
                 __float2bfloat16(v.z), __float2bfloat16(v.w)};
    *(uint2*)(dst + i) = *(uint2*)o;
  }
}

// ---------------------------------------------------------------------------
// fwd: per 64-row stripe, per path: L1 -> X(LDS); L2 chunked over h with
// L3 folded into the epilogue; writes Xbf/Ybf (h path), mu/Qd -> out.
// grid (64, 2), block 256. LDS ~112 KB -> 1 block/CU.
// ---------------------------------------------------------------------------
__global__ __launch_bounds__(256) void fwd(
    const float* __restrict__ states,
    const bf16* __restrict__ W1bf, const float* __restrict__ b1,
    const bf16* __restrict__ W2bf, const float* __restrict__ b2,
    const bf16* __restrict__ W3bf, const float* __restrict__ b3,
    const bf16* __restrict__ V1bf, const float* __restrict__ c1,
    const bf16* __restrict__ V2bf, const float* __restrict__ c2,
    const bf16* __restrict__ V3bf, const float* __restrict__ c3,
    bf16* __restrict__ Xbf, bf16* __restrict__ Ybf, float* __restrict__ out) {
  __shared__ __align__(16) bf16 mus[64 * 72];     //  9216 B
  __shared__ __align__(16) bf16 Xres[64 * 520];   // 66560 B
  __shared__ __align__(16) bf16 Bs[128 * 72];     // 18432 B
  __shared__ __align__(16) bf16 Ych[64 * 136];    // 17408 B
  const int bt = blockIdx.x * 64;
  const int path = blockIdx.y;                    // 0 = h (W), 1 = Q (V)
  const bf16* Wa = path ? V1bf : W1bf;
  const float* ba = path ? c1 : b1;
  const bf16* Wb = path ? V2bf : W2bf;
  const float* bbv = path ? c2 : b2;
  const bf16* Wc = path ? V3bf : W3bf;
  const float* bcv = path ? c3 : b3;
  const int t = threadIdx.x;
  const int lane = t & 63;
  const int w = t >> 6, wm = w & 1, wn = w >> 1;
  const int c = lane & 15, q = lane >> 4;

  // stage mu (64 x 64) -> bf16, stride 72
  {
    int row = t >> 2, cg = (t & 3) * 16;
    bf16 o[16];
#pragma unroll
    for (int j = 0; j < 16; j += 4) {
      float4 v = *(const float4*)(states + (size_t)(bt + row) * 128 + cg + j);
      o[j] = __float2bfloat16(v.x); o[j + 1] = __float2bfloat16(v.y);
      o[j + 2] = __float2bfloat16(v.z); o[j + 3] = __float2bfloat16(v.w);
    }
    *(uint4*)(mus + row * 72 + cg) = *(const uint4*)o;
    *(uint4*)(mus + row * 72 + cg + 8) = *(const uint4*)(o + 8);
  }
  __syncthreads();

  // ---- L1: X = tanh(mu @ Wa^T + ba), K=64, 4 N-chunks of 128 ----
  for (int nch = 0; nch < 4; ++nch) {
    if (nch) __syncthreads();
#pragma unroll
    for (int i = 0; i < 4; ++i) {
      int g = t + i * 256;
      int row = g >> 3, kb = (g & 7) * 8;
      *(uint4*)(Bs + row * 72 + kb) =
          *(const uint4*)(Wa + (size_t)(nch * 128 + row) * 64 + kb);
    }
    __syncthreads();
    f32x4 acc1[2][4] = {};
#pragma unroll
    for (int s = 0; s < 2; ++s) {
      bf16x8 af[2], bfr[4];
#pragma unroll
      for (int mt = 0; mt < 2; ++mt)
        af[mt] = BC8(mus + (wm * 32 + mt * 16 + c) * 72 + s * 32 + q * 8);
#pragma unroll
      for (int nt = 0; nt < 4; ++nt)
        bfr[nt] = BC8(Bs + (wn * 64 + nt * 16 + c) * 72 + s * 32 + q * 8);
#pragma unroll
      for (int mt = 0; mt < 2; ++mt)
#pragma unroll
        for (int nt = 0; nt < 4; ++nt)
          acc1[mt][nt] = __builtin_amdgcn_mfma_f32_16x16x32_bf16(
              af[mt], bfr[nt], acc1[mt][nt], 0, 0, 0);
    }
#pragma unroll
    for (int nt = 0; nt < 4; ++nt) {
      int cl = wn * 64 + nt * 16 + c;
      int col = nch * 128 + cl;
      float bias = ba[col];
#pragma unroll
      for (int mt = 0; mt < 2; ++mt)
#pragma unroll
        for (int r = 0; r < 4; ++r) {
          int row = wm * 32 + mt * 16 + q * 4 + r;
          float x = tanhf(acc1[mt][nt][r] + bias);
          Xres[row * 520 + col] = __float2bfloat16(x);
          if (!path) Xbf[(size_t)(bt + row) * HH + col] = __float2bfloat16(x);
        }
    }
  }
  __syncthreads();

  // ---- L2 + L3-fold: Y chunk = tanh(X @ Wb^T), acc3 += Ych @ Wc^T ----
  f32x4 acc3[2][2] = {};
  for (int hch = 0; hch < 4; ++hch) {
    f32x4 acc2[2][4] = {};
    for (int kc = 0; kc < 8; ++kc) {
      __syncthreads();
#pragma unroll
      for (int i = 0; i < 4; ++i) {
        int g = t + i * 256;
        int row = g >> 3, kb = (g & 7) * 8;
        *(uint4*)(Bs + row * 72 + kb) =
            *(const uint4*)(Wb + (size_t)(hch * 128 + row) * HH + kc * 64 + kb);
      }
      __syncthreads();
#pragma unroll
      for (int s = 0; s < 2; ++s) {
        bf16x8 af[2], bfr[4];
#pragma unroll
        for (int mt = 0; mt < 2; ++mt)
          af[mt] = BC8(Xres + (wm * 32 + mt * 16 + c) * 520 + kc * 64 + s * 32 + q * 8);
#pragma unroll
        for (int nt = 0; nt < 4; ++nt)
          bfr[nt] = BC8(Bs + (wn * 64 + nt * 16 + c) * 72 + s * 32 + q * 8);
#pragma unroll
        for (int mt = 0; mt < 2; ++mt)
#pragma unroll
          for (int nt = 0; nt < 4; ++nt)
            acc2[mt][nt] = __builtin_amdgcn_mfma_f32_16x16x32_bf16(
                af[mt], bfr[nt], acc2[mt][nt], 0, 0, 0);
      }
    }
    __syncthreads();
#pragma unroll
    for (int nt = 0; nt < 4; ++nt) {
      int hl = wn * 64 + nt * 16 + c;
      int h = hch * 128 + hl;
      float bias = bbv[h];
#pragma unroll
      for (int mt = 0; mt < 2; ++mt)
#pragma unroll
        for (int r = 0; r < 4; ++r) {
          int row = wm * 32 + mt * 16 + q * 4 + r;
          float y = tanhf(acc2[mt][nt][r] + bias);
          Ych[row * 136 + hl] = __float2bfloat16(y);
          if (!path) Ybf[(size_t)(bt + row) * HH + h] = __float2bfloat16(y);
        }
    }
    __syncthreads();
    // L3 fold over this h-chunk (K=128): B-frags direct from global Wc
#pragma unroll
    for (int s3 = 0; s3 < 4; ++s3) {
      bf16x8 af3[2], bf3[2];
#pragma unroll
      for (int mt = 0; mt < 2; ++mt)
        af3[mt] = BC8(Ych + (wm * 32 + mt * 16 + c) * 136 + s3 * 32 + q * 8);
#pragma unroll
      for (int nt = 0; nt < 2; ++nt)
        bf3[nt] = BC8(Wc + (size_t)(wn * 32 + nt * 16 + c) * HH + hch * 128 + s3 * 32 + q * 8);
#pragma unroll
      for (int mt = 0; mt < 2; ++mt)
#pragma unroll
        for (int nt = 0; nt < 2; ++nt)
          acc3[mt][nt] = __builtin_amdgcn_mfma_f32_16x16x32_bf16(
              af3[mt], bf3[nt], acc3[mt][nt], 0, 0, 0);
    }
  }
  // L3 epilogue -> out (f32). path0: mu_drift cols 0..63; path1: softplus Qd.
#pragma unroll
  for (int nt = 0; nt < 2; ++nt) {
    int o = wn * 32 + nt * 16 + c;
    float bias = bcv[o];
#pragma unroll
    for (int mt = 0; mt < 2; ++mt)
#pragma unroll
      for (int r = 0; r < 4; ++r) {
        int row = wm * 32 + mt * 16 + q * 4 + r;
        float v = acc3[mt][nt][r] + bias;
        if (path) {
          v = fmaxf(v, 0.0f) + log1pf(expf(-fabsf(v)));
          out[(size_t)(bt + row) * 128 + 64 + o] = v;
        } else {
          out[(size_t)(bt + row) * 128 + o] = v;
        }
      }
  }
}

// ---------------------------------------------------------------------------
// k4 v8: grid (2048), R12's 128x128/BK=64 inner structure, hp in 0..3 looped
// inside; epilogue folds into jp regs; final reduce writes out directly.
// LDS ~63.5 KB -> 2 blocks/CU.
// ---------------------------------------------------------------------------
__global__ __launch_bounds__(256) void k4_gemm(
    const bf16* __restrict__ Xbf, const bf16* __restrict__ Ybf,
    const bf16* __restrict__ W1T, const bf16* __restrict__ W2bf,
    const float* __restrict__ W3, const float* __restrict__ states,
    float* __restrict__ out) {
  __shared__ __align__(16) bf16 As[128 * 72];
  __shared__ __align__(16) bf16 Bs[128 * 72];
  __shared__ __align__(16) bf16 w3s[64 * 136];
  __shared__ __align__(16) float d1f[2 * 512];
  __shared__ __align__(16) float d2f[2 * 512];
  __shared__ float red[256];
  const int bt = blockIdx.x;                 // b-pair
  const int t = threadIdx.x;
  const int lane = t & 63;
  const int w = t >> 6, wm = w & 1, wn = w >> 1;
  const int c = lane & 15, q = lane >> 4;

  // stage d1f/d2f (2 rows x 512 each), vectorized
  {
    int br = t >> 6, col = (t & 63) * 8;     // 8 elems/thread covers 2x512
    uint4 xr = *(const uint4*)(Xbf + (size_t)(bt * 2 + br) * HH + col);
    uint4 yr = *(const uint4*)(Ybf + (size_t)(bt * 2 + br) * HH + col);
    const unsigned short* xs = (const unsigned short*)&xr;
    const unsigned short* ys = (const unsigned short*)&yr;
#pragma unroll
    for (int j = 0; j < 8; ++j) {
      float x = u16tof(xs[j]);
      float y = u16tof(ys[j]);
      d1f[br * 512 + col + j] = 1.0f - x * x;
      d2f[br * 512 + col + j] = 1.0f - y * y;
    }
  }
  __syncthreads();

  float jp[4][4] = {};
  for (int hp = 0; hp < 4; ++hp) {
    const int h0 = hp * 128;
    f32x4 acc[4][4] = {};
    for (int kc = 0; kc < 8; ++kc) {
      __syncthreads();
      // Bs: 128 x 64 pure copy
#pragma unroll
      for (int i = 0; i < 4; ++i) {
        int g = t + i * 256;
        int row = g >> 3, kb = (g & 7) * 8;
        *(uint4*)(Bs + row * 72 + kb) =
            *(const uint4*)(W2bf + (size_t)(h0 + row) * HH + kc * 64 + kb);
      }
      // As: m = bb*64 + dl; A = d1f * W1T
#pragma unroll
      for (int i = 0; i < 4; ++i) {
        int g = t + i * 256;
        int m = g >> 3, kb = (g & 7) * 8;
        int bb = m >> 6, dl = m & 63;
        uint4 w1r = *(const uint4*)(W1T + (size_t)dl * HH + kc * 64 + kb);
        const unsigned short* ws_ = (const unsigned short*)&w1r;
        const float* dp = d1f + bb * 512 + kc * 64 + kb;
        bf16 oa[8];
#pragma unroll
        for (int j = 0; j < 8; ++j)
          oa[j] = __float2bfloat16(dp[j] * u16tof(ws_[j]));
        *(uint4*)(As + m * 72 + kb) = *(const uint4*)oa;
      }
      // w3s once per hp
      if (kc == 0) {
#pragma unroll
        for (int i = 0; i < 8; ++i) {
          int e = (t + i * 256) * 4;
          int dl = e >> 7, hl = e & 127;
          float4 v = *(const float4*)(W3 + (size_t)dl * HH + h0 + hl);
          bf16 o[4] = {__float2bfloat16(v.x), __float2bfloat16(v.y),
                       __float2bfloat16(v.z), __float2bfloat16(v.w)};
          *(uint2*)(w3s + dl * 136 + hl) = *(uint2*)o;
        }
      }
      __syncthreads();
#pragma unroll
      for (int s = 0; s < 2; ++s) {
        bf16x8 af[4], bfr[4];
#pragma unroll
        for (int mt = 0; mt < 4; ++mt)
          af[mt] = BC8(As + (wm * 64 + mt * 16 + c) * 72 + s * 32 + q * 8);
#pragma unroll
        for (int nt = 0; nt < 4; ++nt)
          bfr[nt] = BC8(Bs + (wn * 64 + nt * 16 + c) * 72 + s * 32 + q * 8);
#pragma unroll
        for (int mt = 0; mt < 4; ++mt)
#pragma unroll
          for (int nt = 0; nt < 4; ++nt)
            acc[mt][nt] = __builtin_amdgcn_mfma_f32_16x16x32_bf16(
                af[mt], bfr[nt], acc[mt][nt], 0, 0, 0);
      }
    }
    // fold this h-plane into jp
#pragma unroll
    for (int mt = 0; mt < 4; ++mt) {
#pragma unroll
      for (int r = 0; r < 4; ++r) {
        int m = wm * 64 + mt * 16 + q * 4 + r;
        int bb = m >> 6, dl = m & 63;
        float v = 0.f;
#pragma unroll
        for (int nt = 0; nt < 4; ++nt) {
          int n = wn * 64 + nt * 16 + c;
          v += acc[mt][nt][r] * d2f[bb * 512 + h0 + n] * bf2f(w3s[dl * 136 + n]);
        }
        jp[mt][r] += v;
      }
    }
  }

  // final reduce over col-lanes, cross-wave via red, write out
#pragma unroll
  for (int mt = 0; mt < 4; ++mt)
#pragma unroll
    for (int r = 0; r < 4; ++r) {
      float v = jp[mt][r];
      v += __shfl_xor(v, 1);
      v += __shfl_xor(v, 2);
      v += __shfl_xor(v, 4);
      v += __shfl_xor(v, 8);
      if (c == 0) red[wn * 128 + wm * 64 + mt * 16 + q * 4 + r] = v;
    }
  __syncthreads();
  if (t < 128) {
    float J = red[t] + red[128 + t];
    int bl = bt * 2 + (t >> 6), d = t & 63;
    float sig = states[(size_t)bl * 128 + 64 + d];
    float qd = out[(size_t)bl * 128 + 64 + d];
    out[(size_t)bl * 128 + 64 + d] = 2.0f * J * sig + qd;
  }
}

extern "C" void kernel_launch(void* const* d_in, const int* in_sizes, int n_in,
                              void* d_out, int out_size, void* d_ws, size_t ws_size,
                              hipStream_t stream) {
  // inputs: 0:t 1:states 2:W1 3:b1 4:W2 5:b2 6:W3 7:b3 8:V1 9:c1 10:V2 11:c2 12:V3 13:c3
  const float* states = (const float*)d_in[1];
  const float* W1 = (const float*)d_in[2];
  const float* b1 = (const float*)d_in[3];
  const float* W2 = (const float*)d_in[4];
  const float* b2 = (const float*)d_in[5];
  const float* W3 = (const float*)d_in[6];
  const float* b3 = (const float*)d_in[7];
  const float* V1 = (const float*)d_in[8];
  const float* c1 = (const float*)d_in[9];
  const float* V2 = (const float*)d_in[10];
  const float* c2 = (const float*)d_in[11];
  const float* V3 = (const float*)d_in[12];
  const float* c3 = (const float*)d_in[13];
  float* out = (float*)d_out;

  bf16* Xbf = (bf16*)d_ws;                         // B*H  (4 MB)
  bf16* Ybf = Xbf + (size_t)BB * HH;               // B*H  (4 MB)
  bf16* W2bf = Ybf + (size_t)BB * HH;              // H*H  (0.5 MB)
  bf16* V2bf = W2bf + (size_t)HH * HH;             // H*H  (0.5 MB)
  bf16* W1T = V2bf + (size_t)HH * HH;              // 64x512
  bf16* W1bf = W1T + (size_t)DD * HH;              // 512x64
  bf16* V1bf = W1bf + (size_t)HH * DD;             // 512x64
  bf16* W3bf = V1bf + (size_t)HH * DD;             // 64x512
  bf16* V3bf = W3bf + (size_t)DD * HH;             // 64x512

  cvt_weights<<<dim3(672), 256, 0, stream>>>(W2, V2, W1, V1, W3, V3,
                                             W2bf, V2bf, W1T, W1bf, V1bf, W3bf, V3bf);
  fwd<<<dim3(64, 2), 256, 0, stream>>>(states, W1bf, b1, W2bf, b2, W3bf, b3,
                                       V1bf, c1, V2bf, c2, V3bf, c3,
                                       Xbf, Ybf, out);
  k4_gemm<<<dim3(2048), 256, 0, stream>>>(Xbf, Ybf, W1T, W2bf, W3, states, out);
}

// Round 15
// 467.170 us; speedup vs baseline: 1.3898x; 1.0460x over previous
//
#include <hip/hip_runtime.h>
#include <hip/hip_bf16.h>

#define BB 4096
#define DD 64
#define HH 512

typedef __hip_bfloat16 bf16;
typedef __attribute__((ext_vector_type(8))) short bf16x8;
typedef __attribute__((ext_vector_type(4))) float f32x4;

__device__ __forceinline__ float bf2f(bf16 x) { return __bfloat162float(x); }
__device__ __forceinline__ float u16tof(unsigned short u) {
  union { unsigned int i; float f; } v; v.i = ((unsigned int)u) << 16; return v.f;
}
#define BC8(p) __builtin_bit_cast(bf16x8, *(const uint4*)(p))

// ws: Xbf | Ybf (B*H bf16) | W2bf | V2bf (H*H bf16) |
//     W1T | W1bf | V1bf | W3bf | V3bf | Jpart (4 x B x 64 f32)  ~13.3 MB
// fwd writes mu -> out[:, :64] and Qd -> out[:, 64:]; combine RMWs out[:, 64:].

// ---------------------------------------------------------------------------
// cvt: [0,256) W2bf; [256,512) V2bf; [512,544) W1T[d*512+k]=W1[k*64+d];
//      [544,672): natural bf16 cvt of W1, V1, W3, V3.
// ---------------------------------------------------------------------------
__global__ __launch_bounds__(256) void cvt_weights(
    const float* __restrict__ W2, const float* __restrict__ V2,
    const float* __restrict__ W1, const float* __restrict__ V1,
    const float* __restrict__ W3, const float* __restrict__ V3,
    bf16* __restrict__ W2bf, bf16* __restrict__ V2bf, bf16* __restrict__ W1T,
    bf16* __restrict__ W1bf, bf16* __restrict__ V1bf,
    bf16* __restrict__ W3bf, bf16* __restrict__ V3bf) {
  int blk = blockIdx.x, t = threadIdx.x;
  if (blk < 512) {
    const float* src = (blk < 256) ? W2 : V2;
    bf16* dst = (blk < 256) ? W2bf : V2bf;
    int i = ((blk & 255) * 256 + t) * 4;
    float4 v = *(const float4*)(src + i);
    bf16 o[4] = {__float2bfloat16(v.x), __float2bfloat16(v.y),
                 __float2bfloat16(v.z), __float2bfloat16(v.w)};
    *(uint2*)(dst + i) = *(uint2*)o;
  } else if (blk < 544) {
    int e = (blk - 512) * 1024 + t * 4;
    int d = e >> 9, k0 = e & 511;
    bf16 o[4];
#pragma unroll
    for (int j = 0; j < 4; ++j) o[j] = __float2bfloat16(W1[(size_t)(k0 + j) * 64 + d]);
    *(uint2*)(W1T + e) = *(uint2*)o;
  } else {
    int which = (blk - 544) >> 5;
    int local = (blk - 544) & 31;
    const float* src = (which == 0) ? W1 : (which == 1) ? V1 : (which == 2) ? W3 : V3;
    bf16* dst = (which == 0) ? W1bf : (which == 1) ? V1bf : (which == 2) ? W3bf : V3bf;
    int i = (local * 256 + t) * 4;
    float4 v = *(const float4*)(src + i);
    bf16 o[4] = {__float2bfloat16(v.x), __float2bfloat16(v.y),
                 __float2bfloat16(v.z), __float2bfloat16(v.w)};
    *(uint2*)(dst + i) = *(uint2*)o;
  }
}

// ---------------------------------------------------------------------------
// fwd: per 64-row stripe, per path: L1 -> X(LDS); L2 chunked over h with
// L3 folded into the epilogue; writes Xbf/Ybf (h path), mu/Qd -> out.
// grid (64, 2), block 256.
// ---------------------------------------------------------------------------
__global__ __launch_bounds__(256) void fwd(
    const float* __restrict__ states,
    const bf16* __restrict__ W1bf, const float* __restrict__ b1,
    const bf16* __restrict__ W2bf, const float* __restrict__ b2,
    const bf16* __restrict__ W3bf, const float* __restrict__ b3,
    const bf16* __restrict__ V1bf, const float* __restrict__ c1,
    const bf16* __restrict__ V2bf, const float* __restrict__ c2,
    const bf16* __restrict__ V3bf, const float* __restrict__ c3,
    bf16* __restrict__ Xbf, bf16* __restrict__ Ybf, float* __restrict__ out) {
  __shared__ __align__(16) bf16 mus[64 * 72];
  __shared__ __align__(16) bf16 Xres[64 * 520];
  __shared__ __align__(16) bf16 Bs[128 * 72];
  __shared__ __align__(16) bf16 Ych[64 * 136];
  const int bt = blockIdx.x * 64;
  const int path = blockIdx.y;
  const bf16* Wa = path ? V1bf : W1bf;
  const float* ba = path ? c1 : b1;
  const bf16* Wb = path ? V2bf : W2bf;
  const float* bbv = path ? c2 : b2;
  const bf16* Wc = path ? V3bf : W3bf;
  const float* bcv = path ? c3 : b3;
  const int t = threadIdx.x;
  const int lane = t & 63;
  const int w = t >> 6, wm = w & 1, wn = w >> 1;
  const int c = lane & 15, q = lane >> 4;

  {
    int row = t >> 2, cg = (t & 3) * 16;
    bf16 o[16];
#pragma unroll
    for (int j = 0; j < 16; j += 4) {
      float4 v = *(const float4*)(states + (size_t)(bt + row) * 128 + cg + j);
      o[j] = __float2bfloat16(v.x); o[j + 1] = __float2bfloat16(v.y);
      o[j + 2] = __float2bfloat16(v.z); o[j + 3] = __float2bfloat16(v.w);
    }
    *(uint4*)(mus + row * 72 + cg) = *(const uint4*)o;
    *(uint4*)(mus + row * 72 + cg + 8) = *(const uint4*)(o + 8);
  }
  __syncthreads();

  // L1: X = tanh(mu @ Wa^T + ba), K=64
  for (int nch = 0; nch < 4; ++nch) {
    if (nch) __syncthreads();
#pragma unroll
    for (int i = 0; i < 4; ++i) {
      int g = t + i * 256;
      int row = g >> 3, kb = (g & 7) * 8;
      *(uint4*)(Bs + row * 72 + kb) =
          *(const uint4*)(Wa + (size_t)(nch * 128 + row) * 64 + kb);
    }
    __syncthreads();
    f32x4 acc1[2][4] = {};
#pragma unroll
    for (int s = 0; s < 2; ++s) {
      bf16x8 af[2], bfr[4];
#pragma unroll
      for (int mt = 0; mt < 2; ++mt)
        af[mt] = BC8(mus + (wm * 32 + mt * 16 + c) * 72 + s * 32 + q * 8);
#pragma unroll
      for (int nt = 0; nt < 4; ++nt)
        bfr[nt] = BC8(Bs + (wn * 64 + nt * 16 + c) * 72 + s * 32 + q * 8);
#pragma unroll
      for (int mt = 0; mt < 2; ++mt)
#pragma unroll
        for (int nt = 0; nt < 4; ++nt)
          acc1[mt][nt] = __builtin_amdgcn_mfma_f32_16x16x32_bf16(
              af[mt], bfr[nt], acc1[mt][nt], 0, 0, 0);
    }
#pragma unroll
    for (int nt = 0; nt < 4; ++nt) {
      int cl = wn * 64 + nt * 16 + c;
      int col = nch * 128 + cl;
      float bias = ba[col];
#pragma unroll
      for (int mt = 0; mt < 2; ++mt)
#pragma unroll
        for (int r = 0; r < 4; ++r) {
          int row = wm * 32 + mt * 16 + q * 4 + r;
          float x = tanhf(acc1[mt][nt][r] + bias);
          Xres[row * 520 + col] = __float2bfloat16(x);
          if (!path) Xbf[(size_t)(bt + row) * HH + col] = __float2bfloat16(x);
        }
    }
  }
  __syncthreads();

  // L2 + L3-fold
  f32x4 acc3[2][2] = {};
  for (int hch = 0; hch < 4; ++hch) {
    f32x4 acc2[2][4] = {};
    for (int kc = 0; kc < 8; ++kc) {
      __syncthreads();
#pragma unroll
      for (int i = 0; i < 4; ++i) {
        int g = t + i * 256;
        int row = g >> 3, kb = (g & 7) * 8;
        *(uint4*)(Bs + row * 72 + kb) =
            *(const uint4*)(Wb + (size_t)(hch * 128 + row) * HH + kc * 64 + kb);
      }
      __syncthreads();
#pragma unroll
      for (int s = 0; s < 2; ++s) {
        bf16x8 af[2], bfr[4];
#pragma unroll
        for (int mt = 0; mt < 2; ++mt)
          af[mt] = BC8(Xres + (wm * 32 + mt * 16 + c) * 520 + kc * 64 + s * 32 + q * 8);
#pragma unroll
        for (int nt = 0; nt < 4; ++nt)
          bfr[nt] = BC8(Bs + (wn * 64 + nt * 16 + c) * 72 + s * 32 + q * 8);
#pragma unroll
        for (int mt = 0; mt < 2; ++mt)
#pragma unroll
          for (int nt = 0; nt < 4; ++nt)
            acc2[mt][nt] = __builtin_amdgcn_mfma_f32_16x16x32_bf16(
                af[mt], bfr[nt], acc2[mt][nt], 0, 0, 0);
      }
    }
    __syncthreads();
#pragma unroll
    for (int nt = 0; nt < 4; ++nt) {
      int hl = wn * 64 + nt * 16 + c;
      int h = hch * 128 + hl;
      float bias = bbv[h];
#pragma unroll
      for (int mt = 0; mt < 2; ++mt)
#pragma unroll
        for (int r = 0; r < 4; ++r) {
          int row = wm * 32 + mt * 16 + q * 4 + r;
          float y = tanhf(acc2[mt][nt][r] + bias);
          Ych[row * 136 + hl] = __float2bfloat16(y);
          if (!path) Ybf[(size_t)(bt + row) * HH + h] = __float2bfloat16(y);
        }
    }
    __syncthreads();
#pragma unroll
    for (int s3 = 0; s3 < 4; ++s3) {
      bf16x8 af3[2], bf3[2];
#pragma unroll
      for (int mt = 0; mt < 2; ++mt)
        af3[mt] = BC8(Ych + (wm * 32 + mt * 16 + c) * 136 + s3 * 32 + q * 8);
#pragma unroll
      for (int nt = 0; nt < 2; ++nt)
        bf3[nt] = BC8(Wc + (size_t)(wn * 32 + nt * 16 + c) * HH + hch * 128 + s3 * 32 + q * 8);
#pragma unroll
      for (int mt = 0; mt < 2; ++mt)
#pragma unroll
        for (int nt = 0; nt < 2; ++nt)
          acc3[mt][nt] = __builtin_amdgcn_mfma_f32_16x16x32_bf16(
              af3[mt], bf3[nt], acc3[mt][nt], 0, 0, 0);
    }
  }
#pragma unroll
  for (int nt = 0; nt < 2; ++nt) {
    int o = wn * 32 + nt * 16 + c;
    float bias = bcv[o];
#pragma unroll
    for (int mt = 0; mt < 2; ++mt)
#pragma unroll
      for (int r = 0; r < 4; ++r) {
        int row = wm * 32 + mt * 16 + q * 4 + r;
        float v = acc3[mt][nt][r] + bias;
        if (path) {
          v = fmaxf(v, 0.0f) + log1pf(expf(-fabsf(v)));
          out[(size_t)(bt + row) * 128 + 64 + o] = v;
        } else {
          out[(size_t)(bt + row) * 128 + o] = v;
        }
      }
  }
}

// ---------------------------------------------------------------------------
// k4 v9: R12's winning skeleton (grid 2048 x 4 hp, 128x128, BK=64, Jpart)
// with As ELIMINATED: A-frags built in registers from d1f(LDS) x W1T(global,
// L1/L2-resident). LDS 42 KB -> 3 blocks/CU. K-loop barriers guard only Bs.
// ---------------------------------------------------------------------------
__global__ __launch_bounds__(256) void k4_gemm(
    const bf16* __restrict__ Xbf, const bf16* __restrict__ Ybf,
    const bf16* __restrict__ W1T, const bf16* __restrict__ W2bf,
    const float* __restrict__ W3, float* __restrict__ Jpart) {
  __shared__ __align__(16) bf16 Bs[128 * 72];      // 18432 B
  __shared__ __align__(16) bf16 w3s[64 * 136];     // 17408 B
  __shared__ __align__(16) float d1f[2 * 512];     //  4096 B
  __shared__ __align__(16) float d2f[2 * 128];     //  1024 B
  __shared__ float red[256];                       //  1024 B
  const int bt = blockIdx.x;                       // b-pair
  const int h0 = blockIdx.y * 128;
  const int t = threadIdx.x;
  const int lane = t & 63;
  const int w = t >> 6, wm = w & 1, wn = w >> 1;
  const int c = lane & 15, q = lane >> 4;

  // d1f = 1 - h1^2 (2 x 512 f32)
#pragma unroll
  for (int i = 0; i < 4; ++i) {
    int e = t + i * 256;
    float x = bf2f(Xbf[(size_t)(bt * 2 + (e >> 9)) * HH + (e & 511)]);
    d1f[e] = 1.0f - x * x;
  }
  // d2f = 1 - h2^2 for this h-tile (2 x 128 f32)
  {
    float y = bf2f(Ybf[(size_t)(bt * 2 + (t >> 7)) * HH + h0 + (t & 127)]);
    d2f[t] = 1.0f - y * y;
  }
  // w3s = bf16(W3[dl, h0+hl]) (64 x 128, stride 136)
#pragma unroll
  for (int i = 0; i < 8; ++i) {
    int e = (t + i * 256) * 4;
    int dl = e >> 7, hl = e & 127;
    float4 v = *(const float4*)(W3 + (size_t)dl * HH + h0 + hl);
    bf16 o[4] = {__float2bfloat16(v.x), __float2bfloat16(v.y),
                 __float2bfloat16(v.z), __float2bfloat16(v.w)};
    *(uint2*)(w3s + dl * 136 + hl) = *(uint2*)o;
  }

  f32x4 acc[4][4] = {};
  for (int kc = 0; kc < 8; ++kc) {
    __syncthreads();   // prev Bs frag reads done (1st iter: staging visible)
    // Bs: 128 x 64 pure copy
#pragma unroll
    for (int i = 0; i < 4; ++i) {
      int g = t + i * 256;
      int row = g >> 3, kb = (g & 7) * 8;
      *(uint4*)(Bs + row * 72 + kb) =
          *(const uint4*)(W2bf + (size_t)(h0 + row) * HH + kc * 64 + kb);
    }
    // preload W1T slices for this kc (global, L1/L2-resident)
    uint4 w1pre[2][4];
#pragma unroll
    for (int s = 0; s < 2; ++s)
#pragma unroll
      for (int mt = 0; mt < 4; ++mt)
        w1pre[s][mt] = *(const uint4*)(W1T + (size_t)(mt * 16 + c) * HH +
                                       kc * 64 + s * 32 + q * 8);
    __syncthreads();
#pragma unroll
    for (int s = 0; s < 2; ++s) {
      // d1 slice for this (s,q): same for all mt
      float dp[8];
#pragma unroll
      for (int j = 0; j < 8; ++j) dp[j] = d1f[wm * 512 + kc * 64 + s * 32 + q * 8 + j];
      bf16x8 af[4], bfr[4];
#pragma unroll
      for (int mt = 0; mt < 4; ++mt) {
        const unsigned short* ws_ = (const unsigned short*)&w1pre[s][mt];
        bf16 oa[8];
#pragma unroll
        for (int j = 0; j < 8; ++j)
          oa[j] = __float2bfloat16(dp[j] * u16tof(ws_[j]));
        af[mt] = __builtin_bit_cast(bf16x8, *(const uint4*)oa);
      }
#pragma unroll
      for (int nt = 0; nt < 4; ++nt)
        bfr[nt] = BC8(Bs + (wn * 64 + nt * 16 + c) * 72 + s * 32 + q * 8);
#pragma unroll
      for (int mt = 0; mt < 4; ++mt)
#pragma unroll
        for (int nt = 0; nt < 4; ++nt)
          acc[mt][nt] = __builtin_amdgcn_mfma_f32_16x16x32_bf16(
              af[mt], bfr[nt], acc[mt][nt], 0, 0, 0);
    }
  }

  // epilogue: v[m] = sum_n C[m,n] * d2f[bb,n] * w3s[dl,n]; reduce over c lanes
#pragma unroll
  for (int mt = 0; mt < 4; ++mt) {
#pragma unroll
    for (int r = 0; r < 4; ++r) {
      int m = wm * 64 + mt * 16 + q * 4 + r;
      int bb = m >> 6, dl = m & 63;
      float v = 0.f;
#pragma unroll
      for (int nt = 0; nt < 4; ++nt) {
        int n = wn * 64 + nt * 16 + c;
        v += acc[mt][nt][r] * d2f[bb * 128 + n] * bf2f(w3s[dl * 136 + n]);
      }
      v += __shfl_xor(v, 1);
      v += __shfl_xor(v, 2);
      v += __shfl_xor(v, 4);
      v += __shfl_xor(v, 8);
      if (c == 0) red[wn * 128 + m] = v;
    }
  }
  __syncthreads();
  if (t < 128) {
    float J = red[t] + red[128 + t];
    Jpart[(size_t)blockIdx.y * (BB * 64) + (size_t)bt * 128 + t] = J;
  }
}

// ---------------------------------------------------------------------------
// combine: out[b,64+d] = 2*(sum of 4 Jpart planes)*sigma + out (Qd stash)
// ---------------------------------------------------------------------------
__global__ __launch_bounds__(256) void combine(
    const float* __restrict__ Jpart, const float* __restrict__ states,
    float* __restrict__ out) {
  int idx = blockIdx.x * 256 + threadIdx.x;
  int b = idx >> 6, d = idx & 63;
  const int plane = BB * 64;
  float J = Jpart[idx] + Jpart[plane + idx] + Jpart[2 * plane + idx] +
            Jpart[3 * plane + idx];
  float sig = states[(size_t)b * 128 + 64 + d];
  float qd = out[(size_t)b * 128 + 64 + d];
  out[(size_t)b * 128 + 64 + d] = 2.0f * J * sig + qd;
}

extern "C" void kernel_launch(void* const* d_in, const int* in_sizes, int n_in,
                              void* d_out, int out_size, void* d_ws, size_t ws_size,
                              hipStream_t stream) {
  // inputs: 0:t 1:states 2:W1 3:b1 4:W2 5:b2 6:W3 7:b3 8:V1 9:c1 10:V2 11:c2 12:V3 13:c3
  const float* states = (const float*)d_in[1];
  const float* W1 = (const float*)d_in[2];
  const float* b1 = (const float*)d_in[3];
  const float* W2 = (const float*)d_in[4];
  const float* b2 = (const float*)d_in[5];
  const float* W3 = (const float*)d_in[6];
  const float* b3 = (const float*)d_in[7];
  const float* V1 = (const float*)d_in[8];
  const float* c1 = (const float*)d_in[9];
  const float* V2 = (const float*)d_in[10];
  const float* c2 = (const float*)d_in[11];
  const float* V3 = (const float*)d_in[12];
  const float* c3 = (const float*)d_in[13];
  float* out = (float*)d_out;

  bf16* Xbf = (bf16*)d_ws;                         // B*H  (4 MB)
  bf16* Ybf = Xbf + (size_t)BB * HH;               // B*H  (4 MB)
  bf16* W2bf = Ybf + (size_t)BB * HH;              // H*H  (0.5 MB)
  bf16* V2bf = W2bf + (size_t)HH * HH;             // H*H  (0.5 MB)
  bf16* W1T = V2bf + (size_t)HH * HH;              // 64x512
  bf16* W1bf = W1T + (size_t)DD * HH;              // 512x64
  bf16* V1bf = W1bf + (size_t)HH * DD;             // 512x64
  bf16* W3bf = V1bf + (size_t)HH * DD;             // 64x512
  bf16* V3bf = W3bf + (size_t)DD * HH;             // 64x512
  float* Jpart = (float*)(V3bf + (size_t)DD * HH); // 4*B*64 f32 (4 MB)

  cvt_weights<<<dim3(672), 256, 0, stream>>>(W2, V2, W1, V1, W3, V3,
                                             W2bf, V2bf, W1T, W1bf, V1bf, W3bf, V3bf);
  fwd<<<dim3(64, 2), 256, 0, stream>>>(states, W1bf, b1, W2bf, b2, W3bf, b3,
                                       V1bf, c1, V2bf, c2, V3bf, c3,
                                       Xbf, Ybf, out);
  k4_gemm<<<dim3(2048, 4), 256, 0, stream>>>(Xbf, Ybf, W1T, W2bf, W3, Jpart);
  combine<<<dim3(1024), 256, 0, stream>>>(Jpart, states, out);
}

// Round 16
// 395.246 us; speedup vs baseline: 1.6427x; 1.1820x over previous
//
#include <hip/hip_runtime.h>
#include <hip/hip_bf16.h>

#define BB 4096
#define DD 64
#define HH 512

typedef __hip_bfloat16 bf16;
typedef __attribute__((ext_vector_type(8))) short bf16x8;
typedef __attribute__((ext_vector_type(4))) float f32x4;

__device__ __forceinline__ float bf2f(bf16 x) { return __bfloat162float(x); }
__device__ __forceinline__ float u16tof(unsigned short u) {
  union { unsigned int i; float f; } v; v.i = ((unsigned int)u) << 16; return v.f;
}
#define BC8(p) __builtin_bit_cast(bf16x8, *(const uint4*)(p))

// ws: Xbf | Ybf (B*H bf16) | W2bf | V2bf (H*H bf16) |
//     W1T | W1bf | V1bf | W3bf | V3bf | Jpart (4 x B x 64 f32)  ~13.3 MB
// fwd writes mu -> out[:, :64] and Qd -> out[:, 64:]; combine RMWs out[:, 64:].

// ---------------------------------------------------------------------------
// cvt: [0,256) W2bf; [256,512) V2bf; [512,544) W1T[d*512+k]=W1[k*64+d];
//      [544,672): natural bf16 cvt of W1, V1, W3, V3.
// ---------------------------------------------------------------------------
__global__ __launch_bounds__(256) void cvt_weights(
    const float* __restrict__ W2, const float* __restrict__ V2,
    const float* __restrict__ W1, const float* __restrict__ V1,
    const float* __restrict__ W3, const float* __restrict__ V3,
    bf16* __restrict__ W2bf, bf16* __restrict__ V2bf, bf16* __restrict__ W1T,
    bf16* __restrict__ W1bf, bf16* __restrict__ V1bf,
    bf16* __restrict__ W3bf, bf16* __restrict__ V3bf) {
  int blk = blockIdx.x, t = threadIdx.x;
  if (blk < 512) {
    const float* src = (blk < 256) ? W2 : V2;
    bf16* dst = (blk < 256) ? W2bf : V2bf;
    int i = ((blk & 255) * 256 + t) * 4;
    float4 v = *(const float4*)(src + i);
    bf16 o[4] = {__float2bfloat16(v.x), __float2bfloat16(v.y),
                 __float2bfloat16(v.z), __float2bfloat16(v.w)};
    *(uint2*)(dst + i) = *(uint2*)o;
  } else if (blk < 544) {
    int e = (blk - 512) * 1024 + t * 4;
    int d = e >> 9, k0 = e & 511;
    bf16 o[4];
#pragma unroll
    for (int j = 0; j < 4; ++j) o[j] = __float2bfloat16(W1[(size_t)(k0 + j) * 64 + d]);
    *(uint2*)(W1T + e) = *(uint2*)o;
  } else {
    int which = (blk - 544) >> 5;
    int local = (blk - 544) & 31;
    const float* src = (which == 0) ? W1 : (which == 1) ? V1 : (which == 2) ? W3 : V3;
    bf16* dst = (which == 0) ? W1bf : (which == 1) ? V1bf : (which == 2) ? W3bf : V3bf;
    int i = (local * 256 + t) * 4;
    float4 v = *(const float4*)(src + i);
    bf16 o[4] = {__float2bfloat16(v.x), __float2bfloat16(v.y),
                 __float2bfloat16(v.z), __float2bfloat16(v.w)};
    *(uint2*)(dst + i) = *(uint2*)o;
  }
}

// ---------------------------------------------------------------------------
// fwd: per 64-row stripe, per path: L1 -> X(LDS); L2 chunked over h with
// L3 folded into the epilogue; writes Xbf/Ybf (h path), mu/Qd -> out.
// grid (64, 2), block 256.   [measured R14/R15: "others" = ~110 us total]
// ---------------------------------------------------------------------------
__global__ __launch_bounds__(256) void fwd(
    const float* __restrict__ states,
    const bf16* __restrict__ W1bf, const float* __restrict__ b1,
    const bf16* __restrict__ W2bf, const float* __restrict__ b2,
    const bf16* __restrict__ W3bf, const float* __restrict__ b3,
    const bf16* __restrict__ V1bf, const float* __restrict__ c1,
    const bf16* __restrict__ V2bf, const float* __restrict__ c2,
    const bf16* __restrict__ V3bf, const float* __restrict__ c3,
    bf16* __restrict__ Xbf, bf16* __restrict__ Ybf, float* __restrict__ out) {
  __shared__ __align__(16) bf16 mus[64 * 72];
  __shared__ __align__(16) bf16 Xres[64 * 520];
  __shared__ __align__(16) bf16 Bs[128 * 72];
  __shared__ __align__(16) bf16 Ych[64 * 136];
  const int bt = blockIdx.x * 64;
  const int path = blockIdx.y;
  const bf16* Wa = path ? V1bf : W1bf;
  const float* ba = path ? c1 : b1;
  const bf16* Wb = path ? V2bf : W2bf;
  const float* bbv = path ? c2 : b2;
  const bf16* Wc = path ? V3bf : W3bf;
  const float* bcv = path ? c3 : b3;
  const int t = threadIdx.x;
  const int lane = t & 63;
  const int w = t >> 6, wm = w & 1, wn = w >> 1;
  const int c = lane & 15, q = lane >> 4;

  {
    int row = t >> 2, cg = (t & 3) * 16;
    bf16 o[16];
#pragma unroll
    for (int j = 0; j < 16; j += 4) {
      float4 v = *(const float4*)(states + (size_t)(bt + row) * 128 + cg + j);
      o[j] = __float2bfloat16(v.x); o[j + 1] = __float2bfloat16(v.y);
      o[j + 2] = __float2bfloat16(v.z); o[j + 3] = __float2bfloat16(v.w);
    }
    *(uint4*)(mus + row * 72 + cg) = *(const uint4*)o;
    *(uint4*)(mus + row * 72 + cg + 8) = *(const uint4*)(o + 8);
  }
  __syncthreads();

  // L1: X = tanh(mu @ Wa^T + ba), K=64
  for (int nch = 0; nch < 4; ++nch) {
    if (nch) __syncthreads();
#pragma unroll
    for (int i = 0; i < 4; ++i) {
      int g = t + i * 256;
      int row = g >> 3, kb = (g & 7) * 8;
      *(uint4*)(Bs + row * 72 + kb) =
          *(const uint4*)(Wa + (size_t)(nch * 128 + row) * 64 + kb);
    }
    __syncthreads();
    f32x4 acc1[2][4] = {};
#pragma unroll
    for (int s = 0; s < 2; ++s) {
      bf16x8 af[2], bfr[4];
#pragma unroll
      for (int mt = 0; mt < 2; ++mt)
        af[mt] = BC8(mus + (wm * 32 + mt * 16 + c) * 72 + s * 32 + q * 8);
#pragma unroll
      for (int nt = 0; nt < 4; ++nt)
        bfr[nt] = BC8(Bs + (wn * 64 + nt * 16 + c) * 72 + s * 32 + q * 8);
#pragma unroll
      for (int mt = 0; mt < 2; ++mt)
#pragma unroll
        for (int nt = 0; nt < 4; ++nt)
          acc1[mt][nt] = __builtin_amdgcn_mfma_f32_16x16x32_bf16(
              af[mt], bfr[nt], acc1[mt][nt], 0, 0, 0);
    }
#pragma unroll
    for (int nt = 0; nt < 4; ++nt) {
      int cl = wn * 64 + nt * 16 + c;
      int col = nch * 128 + cl;
      float bias = ba[col];
#pragma unroll
      for (int mt = 0; mt < 2; ++mt)
#pragma unroll
        for (int r = 0; r < 4; ++r) {
          int row = wm * 32 + mt * 16 + q * 4 + r;
          float x = tanhf(acc1[mt][nt][r] + bias);
          Xres[row * 520 + col] = __float2bfloat16(x);
          if (!path) Xbf[(size_t)(bt + row) * HH + col] = __float2bfloat16(x);
        }
    }
  }
  __syncthreads();

  // L2 + L3-fold
  f32x4 acc3[2][2] = {};
  for (int hch = 0; hch < 4; ++hch) {
    f32x4 acc2[2][4] = {};
    for (int kc = 0; kc < 8; ++kc) {
      __syncthreads();
#pragma unroll
      for (int i = 0; i < 4; ++i) {
        int g = t + i * 256;
        int row = g >> 3, kb = (g & 7) * 8;
        *(uint4*)(Bs + row * 72 + kb) =
            *(const uint4*)(Wb + (size_t)(hch * 128 + row) * HH + kc * 64 + kb);
      }
      __syncthreads();
#pragma unroll
      for (int s = 0; s < 2; ++s) {
        bf16x8 af[2], bfr[4];
#pragma unroll
        for (int mt = 0; mt < 2; ++mt)
          af[mt] = BC8(Xres + (wm * 32 + mt * 16 + c) * 520 + kc * 64 + s * 32 + q * 8);
#pragma unroll
        for (int nt = 0; nt < 4; ++nt)
          bfr[nt] = BC8(Bs + (wn * 64 + nt * 16 + c) * 72 + s * 32 + q * 8);
#pragma unroll
        for (int mt = 0; mt < 2; ++mt)
#pragma unroll
          for (int nt = 0; nt < 4; ++nt)
            acc2[mt][nt] = __builtin_amdgcn_mfma_f32_16x16x32_bf16(
                af[mt], bfr[nt], acc2[mt][nt], 0, 0, 0);
      }
    }
    __syncthreads();
#pragma unroll
    for (int nt = 0; nt < 4; ++nt) {
      int hl = wn * 64 + nt * 16 + c;
      int h = hch * 128 + hl;
      float bias = bbv[h];
#pragma unroll
      for (int mt = 0; mt < 2; ++mt)
#pragma unroll
        for (int r = 0; r < 4; ++r) {
          int row = wm * 32 + mt * 16 + q * 4 + r;
          float y = tanhf(acc2[mt][nt][r] + bias);
          Ych[row * 136 + hl] = __float2bfloat16(y);
          if (!path) Ybf[(size_t)(bt + row) * HH + h] = __float2bfloat16(y);
        }
    }
    __syncthreads();
#pragma unroll
    for (int s3 = 0; s3 < 4; ++s3) {
      bf16x8 af3[2], bf3[2];
#pragma unroll
      for (int mt = 0; mt < 2; ++mt)
        af3[mt] = BC8(Ych + (wm * 32 + mt * 16 + c) * 136 + s3 * 32 + q * 8);
#pragma unroll
      for (int nt = 0; nt < 2; ++nt)
        bf3[nt] = BC8(Wc + (size_t)(wn * 32 + nt * 16 + c) * HH + hch * 128 + s3 * 32 + q * 8);
#pragma unroll
      for (int mt = 0; mt < 2; ++mt)
#pragma unroll
        for (int nt = 0; nt < 2; ++nt)
          acc3[mt][nt] = __builtin_amdgcn_mfma_f32_16x16x32_bf16(
              af3[mt], bf3[nt], acc3[mt][nt], 0, 0, 0);
    }
  }
#pragma unroll
  for (int nt = 0; nt < 2; ++nt) {
    int o = wn * 32 + nt * 16 + c;
    float bias = bcv[o];
#pragma unroll
    for (int mt = 0; mt < 2; ++mt)
#pragma unroll
      for (int r = 0; r < 4; ++r) {
        int row = wm * 32 + mt * 16 + q * 4 + r;
        float v = acc3[mt][nt][r] + bias;
        if (path) {
          v = fmaxf(v, 0.0f) + log1pf(expf(-fabsf(v)));
          out[(size_t)(bt + row) * 128 + 64 + o] = v;
        } else {
          out[(size_t)(bt + row) * 128 + o] = v;
        }
      }
  }
}

// ---------------------------------------------------------------------------
// k4 v6 (R12 verbatim — best measured: 278 us, MfmaUtil 21%, 2 blocks/CU):
// grid (2048 bt, 4 hp), 128x128 tile, BK=64. M = 2b x 64d flatten.
// As = d1f * W1T built in LDS per kc; Bs = W2bf pure copy. Epilogue folds
// d2f(f32) * w3s(bf16), shfl-reduce over cols, write Jpart plane.
// ---------------------------------------------------------------------------
__global__ __launch_bounds__(256) void k4_gemm(
    const bf16* __restrict__ Xbf, const bf16* __restrict__ Ybf,
    const bf16* __restrict__ W1T, const bf16* __restrict__ W2bf,
    const float* __restrict__ W3, float* __restrict__ Jpart) {
  __shared__ __align__(16) bf16 As[128 * 72];      // 18432 B
  __shared__ __align__(16) bf16 Bs[128 * 72];      // 18432 B
  __shared__ __align__(16) bf16 w3s[64 * 136];     // 17408 B
  __shared__ __align__(16) float d1f[2 * 512];     //  4096 B
  __shared__ __align__(16) float d2f[2 * 128];     //  1024 B
  __shared__ float red[256];                       //  1024 B
  const int bt = blockIdx.x;                       // b-pair index
  const int h0 = blockIdx.y * 128;
  const int t = threadIdx.x;
  const int lane = t & 63;
  const int w = t >> 6, wm = w & 1, wn = w >> 1;
  const int c = lane & 15, q = lane >> 4;

  // stage d1f = 1 - h1^2 (2 rows x 512, f32)
#pragma unroll
  for (int i = 0; i < 4; ++i) {
    int e = t + i * 256;
    float x = bf2f(Xbf[(size_t)(bt * 2 + (e >> 9)) * HH + (e & 511)]);
    d1f[e] = 1.0f - x * x;
  }
  // stage d2f = 1 - h2^2 for this h-tile (2 x 128, f32)
  {
    float y = bf2f(Ybf[(size_t)(bt * 2 + (t >> 7)) * HH + h0 + (t & 127)]);
    d2f[t] = 1.0f - y * y;
  }
  // stage w3s = bf16(W3[dl, h0+hl]) (64 x 128, stride 136)
#pragma unroll
  for (int i = 0; i < 8; ++i) {
    int e = (t + i * 256) * 4;
    int dl = e >> 7, hl = e & 127;
    float4 v = *(const float4*)(W3 + (size_t)dl * HH + h0 + hl);
    bf16 o[4] = {__float2bfloat16(v.x), __float2bfloat16(v.y),
                 __float2bfloat16(v.z), __float2bfloat16(v.w)};
    *(uint2*)(w3s + dl * 136 + hl) = *(uint2*)o;
  }
  __syncthreads();

  f32x4 acc[4][4] = {};
  for (int kc = 0; kc < 8; ++kc) {
    // build As (1 mul/elem) + copy Bs
#pragma unroll
    for (int i = 0; i < 4; ++i) {
      int g = t + i * 256;
      int m = g >> 3, kb = (g & 7) * 8;
      int bb = m >> 6, dl = m & 63;
      uint4 w1r = *(const uint4*)(W1T + (size_t)dl * HH + kc * 64 + kb);
      const unsigned short* ws_ = (const unsigned short*)&w1r;
      const float* dp = d1f + bb * 512 + kc * 64 + kb;
      bf16 oa[8];
#pragma unroll
      for (int j = 0; j < 8; ++j)
        oa[j] = __float2bfloat16(dp[j] * u16tof(ws_[j]));
      *(uint4*)(As + m * 72 + kb) = *(const uint4*)oa;
      *(uint4*)(Bs + m * 72 + kb) =
          *(const uint4*)(W2bf + (size_t)(h0 + m) * HH + kc * 64 + kb);
    }
    __syncthreads();
#pragma unroll
    for (int s = 0; s < 2; ++s) {
      bf16x8 af[4], bfr[4];
#pragma unroll
      for (int mt = 0; mt < 4; ++mt)
        af[mt] = BC8(As + (wm * 64 + mt * 16 + c) * 72 + s * 32 + q * 8);
#pragma unroll
      for (int nt = 0; nt < 4; ++nt)
        bfr[nt] = BC8(Bs + (wn * 64 + nt * 16 + c) * 72 + s * 32 + q * 8);
#pragma unroll
      for (int mt = 0; mt < 4; ++mt)
#pragma unroll
        for (int nt = 0; nt < 4; ++nt)
          acc[mt][nt] = __builtin_amdgcn_mfma_f32_16x16x32_bf16(
              af[mt], bfr[nt], acc[mt][nt], 0, 0, 0);
    }
    __syncthreads();
  }

  // epilogue: v[m] = sum_n C[m,n] * d2f[bb,n] * w3s[dl,n]; reduce over c lanes
#pragma unroll
  for (int mt = 0; mt < 4; ++mt) {
#pragma unroll
    for (int r = 0; r < 4; ++r) {
      int m = wm * 64 + mt * 16 + q * 4 + r;
      int bb = m >> 6, dl = m & 63;
      float v = 0.f;
#pragma unroll
      for (int nt = 0; nt < 4; ++nt) {
        int n = wn * 64 + nt * 16 + c;
        v += acc[mt][nt][r] * d2f[bb * 128 + n] * bf2f(w3s[dl * 136 + n]);
      }
      v += __shfl_xor(v, 1);
      v += __shfl_xor(v, 2);
      v += __shfl_xor(v, 4);
      v += __shfl_xor(v, 8);
      if (c == 0) red[wn * 128 + m] = v;
    }
  }
  __syncthreads();
  if (t < 128) {
    float J = red[t] + red[128 + t];
    Jpart[(size_t)blockIdx.y * (BB * 64) + (size_t)bt * 128 + t] = J;
  }
}

// ---------------------------------------------------------------------------
// combine: out[b,64+d] = 2*(sum of 4 Jpart planes)*sigma + out (Qd stash)
// ---------------------------------------------------------------------------
__global__ __launch_bounds__(256) void combine(
    const float* __restrict__ Jpart, const float* __restrict__ states,
    float* __restrict__ out) {
  int idx = blockIdx.x * 256 + threadIdx.x;
  int b = idx >> 6, d = idx & 63;
  const int plane = BB * 64;
  float J = Jpart[idx] + Jpart[plane + idx] + Jpart[2 * plane + idx] +
            Jpart[3 * plane + idx];
  float sig = states[(size_t)b * 128 + 64 + d];
  float qd = out[(size_t)b * 128 + 64 + d];
  out[(size_t)b * 128 + 64 + d] = 2.0f * J * sig + qd;
}

extern "C" void kernel_launch(void* const* d_in, const int* in_sizes, int n_in,
                              void* d_out, int out_size, void* d_ws, size_t ws_size,
                              hipStream_t stream) {
  // inputs: 0:t 1:states 2:W1 3:b1 4:W2 5:b2 6:W3 7:b3 8:V1 9:c1 10:V2 11:c2 12:V3 13:c3
  const float* states = (const float*)d_in[1];
  const float* W1 = (const float*)d_in[2];
  const float* b1 = (const float*)d_in[3];
  const float* W2 = (const float*)d_in[4];
  const float* b2 = (const float*)d_in[5];
  const float* W3 = (const float*)d_in[6];
  const float* b3 = (const float*)d_in[7];
  const float* V1 = (const float*)d_in[8];
  const float* c1 = (const float*)d_in[9];
  const float* V2 = (const float*)d_in[10];
  const float* c2 = (const float*)d_in[11];
  const float* V3 = (const float*)d_in[12];
  const float* c3 = (const float*)d_in[13];
  float* out = (float*)d_out;

  bf16* Xbf = (bf16*)d_ws;                         // B*H  (4 MB)
  bf16* Ybf = Xbf + (size_t)BB * HH;               // B*H  (4 MB)
  bf16* W2bf = Ybf + (size_t)BB * HH;              // H*H  (0.5 MB)
  bf16* V2bf = W2bf + (size_t)HH * HH;             // H*H  (0.5 MB)
  bf16* W1T = V2bf + (size_t)HH * HH;              // 64x512
  bf16* W1bf = W1T + (size_t)DD * HH;              // 512x64
  bf16* V1bf = W1bf + (size_t)HH * DD;             // 512x64
  bf16* W3bf = V1bf + (size_t)HH * DD;             // 64x512
  bf16* V3bf = W3bf + (size_t)DD * HH;             // 64x512
  float* Jpart = (float*)(V3bf + (size_t)DD * HH); // 4*B*64 f32 (4 MB)

  cvt_weights<<<dim3(672), 256, 0, stream>>>(W2, V2, W1, V1, W3, V3,
                                             W2bf, V2bf, W1T, W1bf, V1bf, W3bf, V3bf);
  fwd<<<dim3(64, 2), 256, 0, stream>>>(states, W1bf, b1, W2bf, b2, W3bf, b3,
                                       V1bf, c1, V2bf, c2, V3bf, c3,
                                       Xbf, Ybf, out);
  k4_gemm<<<dim3(2048, 4), 256, 0, stream>>>(Xbf, Ybf, W1T, W2bf, W3, Jpart);
  combine<<<dim3(1024), 256, 0, stream>>>(Jpart, states, out);
}

// Round 17
// 353.116 us; speedup vs baseline: 1.8387x; 1.1193x over previous
//
#include <hip/hip_runtime.h>
#include <hip/hip_bf16.h>

#define BB 4096
#define DD 64
#define HH 512

typedef __hip_bfloat16 bf16;
typedef _Float16 f16;
typedef __attribute__((ext_vector_type(8))) short bf16x8;
typedef __attribute__((ext_vector_type(8))) _Float16 f16x8;
typedef __attribute__((ext_vector_type(4))) float f32x4;

__device__ __forceinline__ float bf2f(bf16 x) { return __bfloat162float(x); }
__device__ __forceinline__ float u16tof(unsigned short u) {
  union { unsigned int i; float f; } v; v.i = ((unsigned int)u) << 16; return v.f;
}
#define BC8(p) __builtin_bit_cast(bf16x8, *(const uint4*)(p))
#define BCH8(p) __builtin_bit_cast(f16x8, *(const uint4*)(p))

// ws: Xbf | Ybf (B*H bf16) | W2bf | V2bf (H*H bf16, fwd) |
//     W1bf | V1bf | W3bf | V3bf (fwd) | W1Th (64x512 f16, k4) |
//     W2h (H*H f16, k4) | Jpart (4 x B x 64 f32)   ~13.9 MB
// fwd writes mu -> out[:, :64] and Qd -> out[:, 64:]; combine RMWs out[:, 64:].

// ---------------------------------------------------------------------------
// cvt: [0,256) W2bf; [256,512) V2bf; [512,544) W1Th[d*512+k]=f16(W1[k*64+d]);
//      [544,672) natural bf16 W1,V1,W3,V3; [672,928) W2h = f16(W2).
// ---------------------------------------------------------------------------
__global__ __launch_bounds__(256) void cvt_weights(
    const float* __restrict__ W2, const float* __restrict__ V2,
    const float* __restrict__ W1, const float* __restrict__ V1,
    const float* __restrict__ W3, const float* __restrict__ V3,
    bf16* __restrict__ W2bf, bf16* __restrict__ V2bf, f16* __restrict__ W1Th,
    bf16* __restrict__ W1bf, bf16* __restrict__ V1bf,
    bf16* __restrict__ W3bf, bf16* __restrict__ V3bf, f16* __restrict__ W2h) {
  int blk = blockIdx.x, t = threadIdx.x;
  if (blk < 512) {
    const float* src = (blk < 256) ? W2 : V2;
    bf16* dst = (blk < 256) ? W2bf : V2bf;
    int i = ((blk & 255) * 256 + t) * 4;
    float4 v = *(const float4*)(src + i);
    bf16 o[4] = {__float2bfloat16(v.x), __float2bfloat16(v.y),
                 __float2bfloat16(v.z), __float2bfloat16(v.w)};
    *(uint2*)(dst + i) = *(uint2*)o;
  } else if (blk < 544) {
    int e = (blk - 512) * 1024 + t * 4;
    int d = e >> 9, k0 = e & 511;
    f16 o[4];
#pragma unroll
    for (int j = 0; j < 4; ++j) o[j] = (f16)W1[(size_t)(k0 + j) * 64 + d];
    *(uint2*)(W1Th + e) = *(uint2*)o;
  } else if (blk < 672) {
    int which = (blk - 544) >> 5;
    int local = (blk - 544) & 31;
    const float* src = (which == 0) ? W1 : (which == 1) ? V1 : (which == 2) ? W3 : V3;
    bf16* dst = (which == 0) ? W1bf : (which == 1) ? V1bf : (which == 2) ? W3bf : V3bf;
    int i = (local * 256 + t) * 4;
    float4 v = *(const float4*)(src + i);
    bf16 o[4] = {__float2bfloat16(v.x), __float2bfloat16(v.y),
                 __float2bfloat16(v.z), __float2bfloat16(v.w)};
    *(uint2*)(dst + i) = *(uint2*)o;
  } else {
    int i = ((blk - 672) * 256 + t) * 4;
    float4 v = *(const float4*)(W2 + i);
    f16 o[4] = {(f16)v.x, (f16)v.y, (f16)v.z, (f16)v.w};
    *(uint2*)(W2h + i) = *(uint2*)o;
  }
}

// ---------------------------------------------------------------------------
// fwd: per 64-row stripe, per path: L1 -> X(LDS); L2 chunked over h with
// L3 folded into the epilogue; writes Xbf/Ybf (h path), mu/Qd -> out.
// grid (64, 2), block 256.   [measured R14-R16: others total ~115 us]
// ---------------------------------------------------------------------------
__global__ __launch_bounds__(256) void fwd(
    const float* __restrict__ states,
    const bf16* __restrict__ W1bf, const float* __restrict__ b1,
    const bf16* __restrict__ W2bf, const float* __restrict__ b2,
    const bf16* __restrict__ W3bf, const float* __restrict__ b3,
    const bf16* __restrict__ V1bf, const float* __restrict__ c1,
    const bf16* __restrict__ V2bf, const float* __restrict__ c2,
    const bf16* __restrict__ V3bf, const float* __restrict__ c3,
    bf16* __restrict__ Xbf, bf16* __restrict__ Ybf, float* __restrict__ out) {
  __shared__ __align__(16) bf16 mus[64 * 72];
  __shared__ __align__(16) bf16 Xres[64 * 520];
  __shared__ __align__(16) bf16 Bs[128 * 72];
  __shared__ __align__(16) bf16 Ych[64 * 136];
  const int bt = blockIdx.x * 64;
  const int path = blockIdx.y;
  const bf16* Wa = path ? V1bf : W1bf;
  const float* ba = path ? c1 : b1;
  const bf16* Wb = path ? V2bf : W2bf;
  const float* bbv = path ? c2 : b2;
  const bf16* Wc = path ? V3bf : W3bf;
  const float* bcv = path ? c3 : b3;
  const int t = threadIdx.x;
  const int lane = t & 63;
  const int w = t >> 6, wm = w & 1, wn = w >> 1;
  const int c = lane & 15, q = lane >> 4;

  {
    int row = t >> 2, cg = (t & 3) * 16;
    bf16 o[16];
#pragma unroll
    for (int j = 0; j < 16; j += 4) {
      float4 v = *(const float4*)(states + (size_t)(bt + row) * 128 + cg + j);
      o[j] = __float2bfloat16(v.x); o[j + 1] = __float2bfloat16(v.y);
      o[j + 2] = __float2bfloat16(v.z); o[j + 3] = __float2bfloat16(v.w);
    }
    *(uint4*)(mus + row * 72 + cg) = *(const uint4*)o;
    *(uint4*)(mus + row * 72 + cg + 8) = *(const uint4*)(o + 8);
  }
  __syncthreads();

  // L1: X = tanh(mu @ Wa^T + ba), K=64
  for (int nch = 0; nch < 4; ++nch) {
    if (nch) __syncthreads();
#pragma unroll
    for (int i = 0; i < 4; ++i) {
      int g = t + i * 256;
      int row = g >> 3, kb = (g & 7) * 8;
      *(uint4*)(Bs + row * 72 + kb) =
          *(const uint4*)(Wa + (size_t)(nch * 128 + row) * 64 + kb);
    }
    __syncthreads();
    f32x4 acc1[2][4] = {};
#pragma unroll
    for (int s = 0; s < 2; ++s) {
      bf16x8 af[2], bfr[4];
#pragma unroll
      for (int mt = 0; mt < 2; ++mt)
        af[mt] = BC8(mus + (wm * 32 + mt * 16 + c) * 72 + s * 32 + q * 8);
#pragma unroll
      for (int nt = 0; nt < 4; ++nt)
        bfr[nt] = BC8(Bs + (wn * 64 + nt * 16 + c) * 72 + s * 32 + q * 8);
#pragma unroll
      for (int mt = 0; mt < 2; ++mt)
#pragma unroll
        for (int nt = 0; nt < 4; ++nt)
          acc1[mt][nt] = __builtin_amdgcn_mfma_f32_16x16x32_bf16(
              af[mt], bfr[nt], acc1[mt][nt], 0, 0, 0);
    }
#pragma unroll
    for (int nt = 0; nt < 4; ++nt) {
      int cl = wn * 64 + nt * 16 + c;
      int col = nch * 128 + cl;
      float bias = ba[col];
#pragma unroll
      for (int mt = 0; mt < 2; ++mt)
#pragma unroll
        for (int r = 0; r < 4; ++r) {
          int row = wm * 32 + mt * 16 + q * 4 + r;
          float x = tanhf(acc1[mt][nt][r] + bias);
          Xres[row * 520 + col] = __float2bfloat16(x);
          if (!path) Xbf[(size_t)(bt + row) * HH + col] = __float2bfloat16(x);
        }
    }
  }
  __syncthreads();

  // L2 + L3-fold
  f32x4 acc3[2][2] = {};
  for (int hch = 0; hch < 4; ++hch) {
    f32x4 acc2[2][4] = {};
    for (int kc = 0; kc < 8; ++kc) {
      __syncthreads();
#pragma unroll
      for (int i = 0; i < 4; ++i) {
        int g = t + i * 256;
        int row = g >> 3, kb = (g & 7) * 8;
        *(uint4*)(Bs + row * 72 + kb) =
            *(const uint4*)(Wb + (size_t)(hch * 128 + row) * HH + kc * 64 + kb);
      }
      __syncthreads();
#pragma unroll
      for (int s = 0; s < 2; ++s) {
        bf16x8 af[2], bfr[4];
#pragma unroll
        for (int mt = 0; mt < 2; ++mt)
          af[mt] = BC8(Xres + (wm * 32 + mt * 16 + c) * 520 + kc * 64 + s * 32 + q * 8);
#pragma unroll
        for (int nt = 0; nt < 4; ++nt)
          bfr[nt] = BC8(Bs + (wn * 64 + nt * 16 + c) * 72 + s * 32 + q * 8);
#pragma unroll
        for (int mt = 0; mt < 2; ++mt)
#pragma unroll
          for (int nt = 0; nt < 4; ++nt)
            acc2[mt][nt] = __builtin_amdgcn_mfma_f32_16x16x32_bf16(
                af[mt], bfr[nt], acc2[mt][nt], 0, 0, 0);
      }
    }
    __syncthreads();
#pragma unroll
    for (int nt = 0; nt < 4; ++nt) {
      int hl = wn * 64 + nt * 16 + c;
      int h = hch * 128 + hl;
      float bias = bbv[h];
#pragma unroll
      for (int mt = 0; mt < 2; ++mt)
#pragma unroll
        for (int r = 0; r < 4; ++r) {
          int row = wm * 32 + mt * 16 + q * 4 + r;
          float y = tanhf(acc2[mt][nt][r] + bias);
          Ych[row * 136 + hl] = __float2bfloat16(y);
          if (!path) Ybf[(size_t)(bt + row) * HH + h] = __float2bfloat16(y);
        }
    }
    __syncthreads();
#pragma unroll
    for (int s3 = 0; s3 < 4; ++s3) {
      bf16x8 af3[2], bf3[2];
#pragma unroll
      for (int mt = 0; mt < 2; ++mt)
        af3[mt] = BC8(Ych + (wm * 32 + mt * 16 + c) * 136 + s3 * 32 + q * 8);
#pragma unroll
      for (int nt = 0; nt < 2; ++nt)
        bf3[nt] = BC8(Wc + (size_t)(wn * 32 + nt * 16 + c) * HH + hch * 128 + s3 * 32 + q * 8);
#pragma unroll
      for (int mt = 0; mt < 2; ++mt)
#pragma unroll
        for (int nt = 0; nt < 2; ++nt)
          acc3[mt][nt] = __builtin_amdgcn_mfma_f32_16x16x32_bf16(
              af3[mt], bf3[nt], acc3[mt][nt], 0, 0, 0);
    }
  }
#pragma unroll
  for (int nt = 0; nt < 2; ++nt) {
    int o = wn * 32 + nt * 16 + c;
    float bias = bcv[o];
#pragma unroll
    for (int mt = 0; mt < 2; ++mt)
#pragma unroll
      for (int r = 0; r < 4; ++r) {
        int row = wm * 32 + mt * 16 + q * 4 + r;
        float v = acc3[mt][nt][r] + bias;
        if (path) {
          v = fmaxf(v, 0.0f) + log1pf(expf(-fabsf(v)));
          out[(size_t)(bt + row) * 128 + 64 + o] = v;
        } else {
          out[(size_t)(bt + row) * 128 + o] = v;
        }
      }
  }
}

// ---------------------------------------------------------------------------
// k4 v10 (fp16): R12/R16 skeleton (grid 2048x4, 128x128, BK=64, Jpart) with
// the GEMM in fp16: d1h (f16 LDS) x W1Th (f16 global) -> As via packed
// v_pk_mul_f16 (no unpack/cvt); Bs pure copy from W2h; mfma_f32_16x16x32_f16.
// Epilogue: d2f (f32) * w3s (f16). LDS ~58 KB -> 2 blocks/CU.
// ---------------------------------------------------------------------------
__global__ __launch_bounds__(256) void k4_gemm(
    const bf16* __restrict__ Xbf, const bf16* __restrict__ Ybf,
    const f16* __restrict__ W1Th, const f16* __restrict__ W2h,
    const float* __restrict__ W3, float* __restrict__ Jpart) {
  __shared__ __align__(16) f16 As[128 * 72];       // 18432 B
  __shared__ __align__(16) f16 Bs[128 * 72];       // 18432 B
  __shared__ __align__(16) f16 w3s[64 * 136];      // 17408 B
  __shared__ __align__(16) f16 d1h[2 * 512];       //  2048 B
  __shared__ __align__(16) float d2f[2 * 128];     //  1024 B
  __shared__ float red[256];                       //  1024 B
  const int bt = blockIdx.x;                       // b-pair index
  const int h0 = blockIdx.y * 128;
  const int t = threadIdx.x;
  const int lane = t & 63;
  const int w = t >> 6, wm = w & 1, wn = w >> 1;
  const int c = lane & 15, q = lane >> 4;

  // stage d1h = f16(1 - h1^2) (2 rows x 512)
#pragma unroll
  for (int i = 0; i < 4; ++i) {
    int e = t + i * 256;
    float x = bf2f(Xbf[(size_t)(bt * 2 + (e >> 9)) * HH + (e & 511)]);
    d1h[e] = (f16)(1.0f - x * x);
  }
  // stage d2f = 1 - h2^2 for this h-tile (2 x 128, f32)
  {
    float y = bf2f(Ybf[(size_t)(bt * 2 + (t >> 7)) * HH + h0 + (t & 127)]);
    d2f[t] = 1.0f - y * y;
  }
  // stage w3s = f16(W3[dl, h0+hl]) (64 x 128, stride 136)
#pragma unroll
  for (int i = 0; i < 8; ++i) {
    int e = (t + i * 256) * 4;
    int dl = e >> 7, hl = e & 127;
    float4 v = *(const float4*)(W3 + (size_t)dl * HH + h0 + hl);
    f16 o[4] = {(f16)v.x, (f16)v.y, (f16)v.z, (f16)v.w};
    *(uint2*)(w3s + dl * 136 + hl) = *(uint2*)o;
  }
  __syncthreads();

  f32x4 acc[4][4] = {};
  for (int kc = 0; kc < 8; ++kc) {
    // build As via packed f16 mul + copy Bs
#pragma unroll
    for (int i = 0; i < 4; ++i) {
      int g = t + i * 256;
      int m = g >> 3, kb = (g & 7) * 8;
      int bb = m >> 6, dl = m & 63;
      f16x8 w1v = BCH8(W1Th + (size_t)dl * HH + kc * 64 + kb);
      f16x8 d1v = BCH8(d1h + bb * 512 + kc * 64 + kb);
      f16x8 av = d1v * w1v;                         // 4x v_pk_mul_f16
      *(uint4*)(As + m * 72 + kb) = __builtin_bit_cast(uint4, av);
      *(uint4*)(Bs + m * 72 + kb) =
          *(const uint4*)(W2h + (size_t)(h0 + m) * HH + kc * 64 + kb);
    }
    __syncthreads();
#pragma unroll
    for (int s = 0; s < 2; ++s) {
      f16x8 af[4], bfr[4];
#pragma unroll
      for (int mt = 0; mt < 4; ++mt)
        af[mt] = BCH8(As + (wm * 64 + mt * 16 + c) * 72 + s * 32 + q * 8);
#pragma unroll
      for (int nt = 0; nt < 4; ++nt)
        bfr[nt] = BCH8(Bs + (wn * 64 + nt * 16 + c) * 72 + s * 32 + q * 8);
#pragma unroll
      for (int mt = 0; mt < 4; ++mt)
#pragma unroll
        for (int nt = 0; nt < 4; ++nt)
          acc[mt][nt] = __builtin_amdgcn_mfma_f32_16x16x32_f16(
              af[mt], bfr[nt], acc[mt][nt], 0, 0, 0);
    }
    __syncthreads();
  }

  // epilogue: v[m] = sum_n C[m,n] * d2f[bb,n] * w3s[dl,n]; reduce over c lanes
#pragma unroll
  for (int mt = 0; mt < 4; ++mt) {
#pragma unroll
    for (int r = 0; r < 4; ++r) {
      int m = wm * 64 + mt * 16 + q * 4 + r;
      int bb = m >> 6, dl = m & 63;
      float v = 0.f;
#pragma unroll
      for (int nt = 0; nt < 4; ++nt) {
        int n = wn * 64 + nt * 16 + c;
        v += acc[mt][nt][r] * d2f[bb * 128 + n] * (float)w3s[dl * 136 + n];
      }
      v += __shfl_xor(v, 1);
      v += __shfl_xor(v, 2);
      v += __shfl_xor(v, 4);
      v += __shfl_xor(v, 8);
      if (c == 0) red[wn * 128 + m] = v;
    }
  }
  __syncthreads();
  if (t < 128) {
    float J = red[t] + red[128 + t];
    Jpart[(size_t)blockIdx.y * (BB * 64) + (size_t)bt * 128 + t] = J;
  }
}

// ---------------------------------------------------------------------------
// combine: out[b,64+d] = 2*(sum of 4 Jpart planes)*sigma + out (Qd stash)
// ---------------------------------------------------------------------------
__global__ __launch_bounds__(256) void combine(
    const float* __restrict__ Jpart, const float* __restrict__ states,
    float* __restrict__ out) {
  int idx = blockIdx.x * 256 + threadIdx.x;
  int b = idx >> 6, d = idx & 63;
  const int plane = BB * 64;
  float J = Jpart[idx] + Jpart[plane + idx] + Jpart[2 * plane + idx] +
            Jpart[3 * plane + idx];
  float sig = states[(size_t)b * 128 + 64 + d];
  float qd = out[(size_t)b * 128 + 64 + d];
  out[(size_t)b * 128 + 64 + d] = 2.0f * J * sig + qd;
}

extern "C" void kernel_launch(void* const* d_in, const int* in_sizes, int n_in,
                              void* d_out, int out_size, void* d_ws, size_t ws_size,
                              hipStream_t stream) {
  // inputs: 0:t 1:states 2:W1 3:b1 4:W2 5:b2 6:W3 7:b3 8:V1 9:c1 10:V2 11:c2 12:V3 13:c3
  const float* states = (const float*)d_in[1];
  const float* W1 = (const float*)d_in[2];
  const float* b1 = (const float*)d_in[3];
  const float* W2 = (const float*)d_in[4];
  const float* b2 = (const float*)d_in[5];
  const float* W3 = (const float*)d_in[6];
  const float* b3 = (const float*)d_in[7];
  const float* V1 = (const float*)d_in[8];
  const float* c1 = (const float*)d_in[9];
  const float* V2 = (const float*)d_in[10];
  const float* c2 = (const float*)d_in[11];
  const float* V3 = (const float*)d_in[12];
  const float* c3 = (const float*)d_in[13];
  float* out = (float*)d_out;

  bf16* Xbf = (bf16*)d_ws;                         // B*H  (4 MB)
  bf16* Ybf = Xbf + (size_t)BB * HH;               // B*H  (4 MB)
  bf16* W2bf = Ybf + (size_t)BB * HH;              // H*H  (0.5 MB)
  bf16* V2bf = W2bf + (size_t)HH * HH;             // H*H  (0.5 MB)
  bf16* W1bf = V2bf + (size_t)HH * HH;             // 512x64
  bf16* V1bf = W1bf + (size_t)HH * DD;             // 512x64
  bf16* W3bf = V1bf + (size_t)HH * DD;             // 64x512
  bf16* V3bf = W3bf + (size_t)DD * HH;             // 64x512
  f16* W1Th = (f16*)(V3bf + (size_t)DD * HH);      // 64x512 f16
  f16* W2h = W1Th + (size_t)DD * HH;               // H*H f16 (0.5 MB)
  float* Jpart = (float*)(W2h + (size_t)HH * HH);  // 4*B*64 f32 (4 MB)

  cvt_weights<<<dim3(928), 256, 0, stream>>>(W2, V2, W1, V1, W3, V3,
                                             W2bf, V2bf, W1Th, W1bf, V1bf,
                                             W3bf, V3bf, W2h);
  fwd<<<dim3(64, 2), 256, 0, stream>>>(states, W1bf, b1, W2bf, b2, W3bf, b3,
                                       V1bf, c1, V2bf, c2, V3bf, c3,
                                       Xbf, Ybf, out);
  k4_gemm<<<dim3(2048, 4), 256, 0, stream>>>(Xbf, Ybf, W1Th, W2h, W3, Jpart);
  combine<<<dim3(1024), 256, 0, stream>>>(Jpart, states, out);
}